// Round 1
// 2525.500 us; speedup vs baseline: 1.4974x; 1.4974x over previous
//
#include <hip/hip_runtime.h>
#include <cstdint>

// ---------------------------------------------------------------------------
// DGDN forward (B=4096). Outputs (f32, concat): x_rec[4096,1,28,28],
// mean[4096,80,16], log_var[4096,80,16], eta[4096,30,7,7,9].
// RNG: JAX threefry2x32, jax_threefry_partitionable=True reconstruction.
// Decoder path: Wexp expansion + dense f32 GEMM + GATHER-unpool (no atomics).
// ---------------------------------------------------------------------------

#define OFF_MEAN 3211264
#define OFF_LV   8454144
#define OFF_ETA  13697024

// ------------------------- threefry2x32 (constexpr) ------------------------
constexpr uint64_t ctf(uint32_t k0, uint32_t k1, uint32_t x0, uint32_t x1) {
  uint32_t ks0 = k0, ks1 = k1, ks2 = k0 ^ k1 ^ 0x1BD11BDAu;
  const int rotA[4] = {13, 15, 26, 6};
  const int rotB[4] = {17, 29, 16, 24};
  x0 += ks0; x1 += ks1;
  for (int g = 0; g < 5; ++g) {
    for (int i = 0; i < 4; ++i) {
      int r = (g & 1) ? rotB[i] : rotA[i];
      x0 += x1;
      x1 = (uint32_t)((x1 << r) | (x1 >> (32 - r)));
      x1 ^= x0;
    }
    uint32_t ka = (g + 1) % 3 == 0 ? ks0 : ((g + 1) % 3 == 1 ? ks1 : ks2);
    uint32_t kb = (g + 2) % 3 == 0 ? ks0 : ((g + 2) % 3 == 1 ? ks1 : ks2);
    x0 += ka;
    x1 += kb + (uint32_t)(g + 1);
  }
  return ((uint64_t)x0 << 32) | (uint64_t)x1;
}

constexpr uint64_t KP_ = ctf(0u, 42u, 0u, 0u);  // k_pool
constexpr uint64_t KU_ = ctf(0u, 42u, 0u, 1u);  // k_unpool
constexpr uint64_t KC_ = ctf(0u, 42u, 0u, 2u);  // k_code
constexpr uint64_t KN_ = ctf(0u, 42u, 0u, 3u);  // k_noise
constexpr uint32_t KPOOL0 = (uint32_t)(KP_ >> 32), KPOOL1 = (uint32_t)KP_;
constexpr uint32_t KUNP0  = (uint32_t)(KU_ >> 32), KUNP1  = (uint32_t)KU_;
constexpr uint32_t KCODE0 = (uint32_t)(KC_ >> 32), KCODE1 = (uint32_t)KC_;
constexpr uint32_t KNOIS0 = (uint32_t)(KN_ >> 32), KNOIS1 = (uint32_t)KN_;

// ------------------------- device threefry + draws -------------------------
__device__ __forceinline__ uint2 tf_dev(uint32_t k0, uint32_t k1, uint32_t x0, uint32_t x1) {
  uint32_t ks2 = k0 ^ k1 ^ 0x1BD11BDAu;
  x0 += k0; x1 += k1;
#define TFR(r) { x0 += x1; x1 = (x1 << (r)) | (x1 >> (32 - (r))); x1 ^= x0; }
  TFR(13) TFR(15) TFR(26) TFR(6)
  x0 += k1;  x1 += ks2 + 1u;
  TFR(17) TFR(29) TFR(16) TFR(24)
  x0 += ks2; x1 += k0 + 2u;
  TFR(13) TFR(15) TFR(26) TFR(6)
  x0 += k0;  x1 += k1 + 3u;
  TFR(17) TFR(29) TFR(16) TFR(24)
  x0 += k1;  x1 += ks2 + 4u;
  TFR(13) TFR(15) TFR(26) TFR(6)
  x0 += ks2; x1 += k0 + 5u;
#undef TFR
  return make_uint2(x0, x1);
}

__device__ __forceinline__ uint32_t rbits32(uint32_t k0, uint32_t k1, uint32_t idx) {
  uint2 r = tf_dev(k0, k1, 0u, idx);
  return r.x ^ r.y;
}

__device__ __forceinline__ float u01_from_bits(uint32_t bits) {
  return __uint_as_float((bits >> 9) | 0x3F800000u) - 1.0f;
}

__device__ __forceinline__ float gumbel_draw(uint32_t k0, uint32_t k1, uint32_t idx) {
  float u01 = u01_from_bits(rbits32(k0, k1, idx));
  float u = fmaxf(__fadd_rn(u01, 1.17549435e-38f), 1.17549435e-38f);
  return -logf(-logf(u));
}

__device__ __forceinline__ float erfinv_xla(float x) {
  float t = __fmul_rn(x, x);
  float w = -log1pf(-t);
  float p;
  if (w < 5.0f) {
    w = __fadd_rn(w, -2.5f);
    p = 2.81022636e-08f;
    p = __fadd_rn(__fmul_rn(p, w), 3.43273939e-07f);
    p = __fadd_rn(__fmul_rn(p, w), -3.5233877e-06f);
    p = __fadd_rn(__fmul_rn(p, w), -4.39150654e-06f);
    p = __fadd_rn(__fmul_rn(p, w), 0.00021858087f);
    p = __fadd_rn(__fmul_rn(p, w), -0.00125372503f);
    p = __fadd_rn(__fmul_rn(p, w), -0.00417768164f);
    p = __fadd_rn(__fmul_rn(p, w), 0.246640727f);
    p = __fadd_rn(__fmul_rn(p, w), 1.50140941f);
  } else {
    w = __fadd_rn(sqrtf(w), -3.0f);
    p = -0.000200214257f;
    p = __fadd_rn(__fmul_rn(p, w), 0.000100950558f);
    p = __fadd_rn(__fmul_rn(p, w), 0.00134934322f);
    p = __fadd_rn(__fmul_rn(p, w), -0.00367342844f);
    p = __fadd_rn(__fmul_rn(p, w), 0.00573950773f);
    p = __fadd_rn(__fmul_rn(p, w), -0.0076224613f);
    p = __fadd_rn(__fmul_rn(p, w), 0.00943887047f);
    p = __fadd_rn(__fmul_rn(p, w), 1.00167406f);
    p = __fadd_rn(__fmul_rn(p, w), 2.83297682f);
  }
  return __fmul_rn(p, x);
}

__device__ __forceinline__ float normal_draw(uint32_t k0, uint32_t k1, uint32_t idx) {
  float u01 = u01_from_bits(rbits32(k0, k1, idx));
  float u = fmaxf(__fadd_rn(__fmul_rn(u01, 2.0f), -0.99999994f), -0.99999994f);
  return __fmul_rn(1.41421356237309515f, erfinv_xla(u));
}

__device__ __forceinline__ float tanh_xla(float x) {
  float ax = fabsf(x);
  float xc = fmaxf(fminf(x, 7.90531110763549805f), -7.90531110763549805f);
  float x2 = __fmul_rn(xc, xc);
  float p = __fmaf_rn(x2, -2.76076847742355e-16f, 2.00018790482477e-13f);
  p = __fmaf_rn(x2, p, -8.60467152213735e-11f);
  p = __fmaf_rn(x2, p, 5.12229709037114e-08f);
  p = __fmaf_rn(x2, p, 1.48572235717979e-05f);
  p = __fmaf_rn(x2, p, 6.37261928875436e-04f);
  p = __fmaf_rn(x2, p, 4.89352455891786e-03f);
  p = __fmul_rn(xc, p);
  float q = __fmaf_rn(x2, 1.19825839466702e-06f, 1.18534705686654e-04f);
  q = __fmaf_rn(x2, q, 2.26843463243900e-03f);
  q = __fmaf_rn(x2, q, 4.89352518554385e-03f);
  return (ax < 0.0004f) ? x : __fdiv_rn(p, q);
}

// ---------------------------------------------------------------------------
// Encoder (UNCHANGED arithmetic — eta/zeta argmaxes depend on exact fp order).
// ---------------------------------------------------------------------------
__global__ __launch_bounds__(256) void k_enc(
    const float* __restrict__ x, const float* __restrict__ enc1_w,
    const float* __restrict__ pw1, const float* __restrict__ pw2,
    const float* __restrict__ enc2_w, const float* __restrict__ h_w,
    const float* __restrict__ h_b, const float* __restrict__ mean_w,
    const float* __restrict__ mean_b, const float* __restrict__ lv_w,
    const float* __restrict__ lv_b,
    float* __restrict__ o_mean, float* __restrict__ o_lv, float* __restrict__ o_eta,
    float* __restrict__ ws_s, unsigned char* __restrict__ ws_z) {
  __shared__ float lds[10240];
  __shared__ float pooled[1470];
  const int b = blockIdx.x, tid = threadIdx.x;

  float* xs  = lds;
  float* w1s = lds + 784;
  float* pp1 = lds + 2704;
  float* pp2 = lds + 2785;
  for (int i = tid; i < 784; i += 256) xs[i] = x[(size_t)b * 784 + i];
  for (int i = tid; i < 1920; i += 256) w1s[i] = enc1_w[i];
  if (tid < 81) { pp1[tid] = pw1[tid]; pp2[tid] = pw2[tid]; }
  __syncthreads();

  for (int idx = tid; idx < 1470; idx += 256) {
    int c = idx / 49, cell = idx - c * 49;
    int n = cell / 7, m = cell - n * 7;
    int yb = n * 3, xb = m * 3;
    float tile[9];
#pragma unroll
    for (int i = 0; i < 9; ++i) tile[i] = 0.f;
    const float* wc = &w1s[c * 64];
#pragma unroll
    for (int r = 0; r < 10; ++r) {
      float xr[10];
#pragma unroll
      for (int i = 0; i < 10; ++i) xr[i] = xs[(yb + r) * 28 + xb + i];
#pragma unroll
      for (int p = 0; p < 3; ++p) {
        int dy = r - p;
        if (dy >= 0 && dy < 8) {
#pragma unroll
          for (int dx = 0; dx < 8; ++dx) {
            float w = wc[dy * 8 + dx];
#pragma unroll
            for (int q = 0; q < 3; ++q) tile[p * 3 + q] += xr[q + dx] * w;
          }
        }
      }
    }
    float h1v[9];
#pragma unroll
    for (int o = 0; o < 9; ++o) {
      float a = 0.f;
#pragma unroll
      for (int t = 0; t < 9; ++t) a += tile[t] * pp1[o * 9 + t];
      h1v[o] = tanh_xla(a);
    }
    float lg[9], mx = -3.4e38f;
#pragma unroll
    for (int o = 0; o < 9; ++o) {
      float a = 0.f;
#pragma unroll
      for (int t = 0; t < 9; ++t) a += h1v[t] * pp2[o * 9 + t];
      lg[o] = a;
      mx = fmaxf(mx, a);
    }
    float ev[9], ssum = 0.f;
#pragma unroll
    for (int o = 0; o < 9; ++o) { ev[o] = expf(__fadd_rn(lg[o], -mx)); ssum += ev[o]; }
    float leta[9];
    size_t ebase = ((size_t)(b * 30 + c) * 49 + cell) * 9;
#pragma unroll
    for (int o = 0; o < 9; ++o) {
      float e = __fdiv_rn(ev[o], ssum);
      o_eta[ebase + o] = e;
      leta[o] = logf(e);
    }
    uint32_t fb = (uint32_t)ebase;
    float best1 = -3.4e38f, best2 = -3.4e38f, pooledv = 0.f;
    int z2 = 0;
#pragma unroll
    for (int t = 0; t < 9; ++t) {
      float v1 = __fadd_rn(leta[t], gumbel_draw(KPOOL0, KPOOL1, fb + t));
      bool t1 = v1 > best1; best1 = t1 ? v1 : best1; pooledv = t1 ? tile[t] : pooledv;
      float v2 = __fadd_rn(leta[t], gumbel_draw(KUNP0, KUNP1, fb + t));
      bool t2 = v2 > best2; best2 = t2 ? v2 : best2; z2 = t2 ? t : z2;
    }
    pooled[idx] = pooledv;
    ws_z[(size_t)b * 1470 + idx] = (unsigned char)z2;
  }

  float* wch = lds;
  float* c2s = lds + 7680;
  float* hs  = lds + 8960;
  for (int ch = 0; ch < 5; ++ch) {
    __syncthreads();
    for (int i = tid; i < 7680; i += 256) wch[i] = enc2_w[ch * 7680 + i];
    __syncthreads();
    int k2l = tid >> 4, pos = tid & 15;
    int uy = pos >> 2, ux = pos & 3;
    float acc = 0.f;
    for (int c = 0; c < 30; ++c) {
      const float* pc = &pooled[c * 49];
      const float* wr = &wch[(k2l * 30 + c) * 16];
#pragma unroll
      for (int dy = 0; dy < 4; ++dy)
#pragma unroll
        for (int dx = 0; dx < 4; ++dx)
          acc += pc[(uy + dy) * 7 + ux + dx] * wr[dy * 4 + dx];
    }
    c2s[(ch * 16 + k2l) * 16 + pos] = acc;
  }
  __syncthreads();

#pragma unroll
  for (int j = 0; j < 5; ++j) {
    int it = tid + j * 256;
    int k2 = it >> 4;
    float d = 0.f;
    const float* wr = &h_w[(size_t)it * 16];
#pragma unroll
    for (int i = 0; i < 16; ++i) d += c2s[k2 * 16 + i] * wr[i];
    hs[it] = tanh_xla(__fadd_rn(d, h_b[it]));
  }
  __syncthreads();

#pragma unroll
  for (int j = 0; j < 5; ++j) {
    int it = tid + j * 256;
    int k2 = it >> 4;
    float dm = 0.f, dl = 0.f;
    const float* wm = &mean_w[(size_t)it * 16];
    const float* wl = &lv_w[(size_t)it * 16];
#pragma unroll
    for (int i = 0; i < 16; ++i) {
      float hv = hs[k2 * 16 + i];
      dm += hv * wm[i];
      dl += hv * wl[i];
    }
    float mean = __fadd_rn(dm, mean_b[it]);
    float lv = __fadd_rn(dl, lv_b[it]);
    size_t gi = (size_t)b * 1280 + it;
    o_mean[gi] = mean;
    o_lv[gi] = lv;
    float stdv = expf(__fmul_rn(0.5f, lv));
    float z = normal_draw(KCODE0, KCODE1, (uint32_t)(b * 1280 + it));
    ws_s[gi] = __fadd_rn(mean, __fmul_rn(stdv, z));
  }
}

// ---------------------------------------------------------------------------
// k_expand: Wexp[k=1280][t=1472] from dec2_w.
// k = k2*16+iy*4+ix ; t = c*49+u*7+v ; val = dec2_w[k2,c,u-iy,v-ix] (valid) else 0
// ---------------------------------------------------------------------------
__global__ __launch_bounds__(256) void k_expand(const float* __restrict__ dec2_w,
                                                float* __restrict__ Wexp) {
  int idx = blockIdx.x * 256 + threadIdx.x;       // < 1280*1472
  int k = idx / 1472, t = idx - k * 1472;
  int k2 = k >> 4, iy = (k >> 2) & 3, ix = k & 3;
  int c = t / 49, cell = t - c * 49;
  int u = cell / 7, v = cell - u * 7;
  int du = u - iy, dv = v - ix;
  float val = 0.f;
  if (t < 1470 && (unsigned)du < 4u && (unsigned)dv < 4u)
    val = dec2_w[((k2 * 30 + c) << 4) + (du << 2) + dv];
  Wexp[idx] = val;
}

// ---------------------------------------------------------------------------
// k_gemm: S2[4096,1472] = A[4096,1280] x Wexp[1280,1472]
// BM=128, BN=64, BK=16, 256 threads, 8x4 micro-tile. k ascending (same
// summation order as the old convT loop, so s2 is numerically ~identical).
// ---------------------------------------------------------------------------
__global__ __launch_bounds__(256) void k_gemm(const float* __restrict__ A,
                                              const float* __restrict__ Bm,
                                              float* __restrict__ C) {
  __shared__ float As[16][132];   // [kk][mm], stride 132 keeps 16B alignment
  __shared__ float Bs[16][64];
  const int tid = threadIdx.x;
  const int n0 = blockIdx.x * 64;     // 23 tiles
  const int m0 = blockIdx.y * 128;    // 32 tiles
  const int tx = tid & 15, ty = tid >> 4;

  float acc[8][4];
#pragma unroll
  for (int i = 0; i < 8; ++i)
#pragma unroll
    for (int j = 0; j < 4; ++j) acc[i][j] = 0.f;

  // staging decomposition
  const int fa_r0 = tid >> 2, fa_c = (tid & 3) << 2;          // A: f=tid, f+256
  const int fb_k = tid >> 4, fb_c = (tid & 15) << 2;          // B: f=tid

  for (int k0 = 0; k0 < 1280; k0 += 16) {
    __syncthreads();
    float4 a0 = *(const float4*)&A[(size_t)(m0 + fa_r0) * 1280 + k0 + fa_c];
    float4 a1 = *(const float4*)&A[(size_t)(m0 + 64 + fa_r0) * 1280 + k0 + fa_c];
    float4 bv = *(const float4*)&Bm[(size_t)(k0 + fb_k) * 1472 + n0 + fb_c];
    As[fa_c + 0][fa_r0] = a0.x;  As[fa_c + 1][fa_r0] = a0.y;
    As[fa_c + 2][fa_r0] = a0.z;  As[fa_c + 3][fa_r0] = a0.w;
    As[fa_c + 0][64 + fa_r0] = a1.x;  As[fa_c + 1][64 + fa_r0] = a1.y;
    As[fa_c + 2][64 + fa_r0] = a1.z;  As[fa_c + 3][64 + fa_r0] = a1.w;
    *(float4*)&Bs[fb_k][fb_c] = bv;
    __syncthreads();

#pragma unroll
    for (int kk = 0; kk < 16; ++kk) {
      float4 av0 = *(const float4*)&As[kk][ty * 8];
      float4 av1 = *(const float4*)&As[kk][ty * 8 + 4];
      float4 bv0 = *(const float4*)&Bs[kk][tx * 4];
      float am[8] = {av0.x, av0.y, av0.z, av0.w, av1.x, av1.y, av1.z, av1.w};
      float bn[4] = {bv0.x, bv0.y, bv0.z, bv0.w};
#pragma unroll
      for (int i = 0; i < 8; ++i)
#pragma unroll
        for (int j = 0; j < 4; ++j) acc[i][j] = __fmaf_rn(am[i], bn[j], acc[i][j]);
    }
  }

#pragma unroll
  for (int i = 0; i < 8; ++i) {
    size_t row = (size_t)(m0 + ty * 8 + i);
    float4 o = make_float4(acc[i][0], acc[i][1], acc[i][2], acc[i][3]);
    *(float4*)&C[row * 1472 + n0 + tx * 4] = o;
  }
}

// ---------------------------------------------------------------------------
// k_unpool (GATHER version, no atomics): for each output pixel (y,x), sum the
// contributions of every tile whose scattered pixel (py,px) lies within the
// 8x8 conv-transpose footprint. Per channel only ~<=4x4 candidate tiles exist
// (tile pitch 3, kernel 8). (py,px) packed per tile in LDS; reads broadcast
// across neighboring lanes -> no bank conflicts, no serialization.
// ---------------------------------------------------------------------------
__global__ __launch_bounds__(256) void k_unpool(
    const float* __restrict__ S2, const unsigned char* __restrict__ ws_z,
    const float* __restrict__ dec1_w, const float* __restrict__ alpha,
    float* __restrict__ o_xrec) {
  __shared__ float w1s[1920];     // dec1_w, [c][8*8]
  __shared__ float vals[1470];    // scattered value per tile
  __shared__ unsigned short pyx[1470];  // packed: py | px<<5
  const int b = blockIdx.x, tid = threadIdx.x;

  for (int i = tid; i < 1920; i += 256) w1s[i] = dec1_w[i];
#pragma unroll
  for (int j = 0; j < 6; ++j) {
    int t = tid + j * 256;
    if (t < 1470) {
      int c = t / 49, cell = t - c * 49;
      int n = cell / 7, m = cell - n * 7;
      int z = ws_z[(size_t)b * 1470 + t];
      int p = z / 3, q = z - p * 3;
      vals[t] = S2[(size_t)b * 1472 + t];
      pyx[t] = (unsigned short)((n * 3 + p) | ((m * 3 + q) << 5));
    }
  }
  __syncthreads();

  float inva = __fdiv_rn(1.0f, alpha[0]);
  for (int pix = tid; pix < 784; pix += 256) {
    int y = pix / 28, x = pix - y * 28;
    // candidate tile rows: need py in [y-7, y]; py = 3n + p, p in [0,3)
    // => n >= ceil((y-9)/3), n <= floor(y/3)
    int nlo = max(0, (y - 7) / 3 - ((y - 7) % 3 < 0 ? 0 : 0));  // see below
    nlo = (y >= 9) ? ((y - 9 + 2) / 3) : 0;
    int nhi = min(6, y / 3);
    int mlo = (x >= 9) ? ((x - 9 + 2) / 3) : 0;
    int mhi = min(6, x / 3);

    float acc = 0.f;
    for (int c = 0; c < 30; ++c) {
      const int cbase = c * 49;
      const float* wc = &w1s[c * 64];
      for (int n = nlo; n <= nhi; ++n) {
        const int t0 = cbase + n * 7;
#pragma unroll 4
        for (int m = mlo; m <= mhi; ++m) {
          int t = t0 + m;
          int pp = pyx[t];
          int dy = y - (pp & 31);
          int dx = x - (pp >> 5);
          bool ok = ((unsigned)dy < 8u) & ((unsigned)dx < 8u);
          float wv = wc[((dy & 7) << 3) + (dx & 7)];
          float vv = ok ? vals[t] : 0.f;
          acc = __fmaf_rn(vv, wv, acc);
        }
      }
    }
    if (y == x) {
      float zn = normal_draw(KNOIS0, KNOIS1, (uint32_t)(b * 784 + pix));
      acc = __fadd_rn(acc, __fmul_rn(inva, zn));
    }
    o_xrec[(size_t)b * 784 + pix] = acc;
  }
}

// ---------------------------------------------------------------------------
extern "C" void kernel_launch(void* const* d_in, const int* in_sizes, int n_in,
                              void* d_out, int out_size, void* d_ws, size_t ws_size,
                              hipStream_t stream) {
  const float* x      = (const float*)d_in[0];
  const float* enc1_w = (const float*)d_in[1];
  const float* pw1    = (const float*)d_in[2];
  const float* pw2    = (const float*)d_in[3];
  const float* enc2_w = (const float*)d_in[4];
  const float* h_w    = (const float*)d_in[5];
  const float* h_b    = (const float*)d_in[6];
  const float* mean_w = (const float*)d_in[7];
  const float* mean_b = (const float*)d_in[8];
  const float* lv_w   = (const float*)d_in[9];
  const float* lv_b   = (const float*)d_in[10];
  const float* dec2_w = (const float*)d_in[11];
  const float* dec1_w = (const float*)d_in[12];
  const float* alpha  = (const float*)d_in[13];

  float* out = (float*)d_out;
  float* o_xrec = out;
  float* o_mean = out + OFF_MEAN;
  float* o_lv   = out + OFF_LV;
  float* o_eta  = out + OFF_ETA;

  // workspace layout (bytes):
  //   ws_s  : 0                .. 20,971,520   (4096x1280 f32)
  //   ws_z  : 20,971,520       .. 26,992,640   (4096x1470 u8)
  //   Wexp  : 26,992,640       .. 34,529,280   (1280x1472 f32)
  //   S2    : 34,529,280       .. 58,646,528   (4096x1472 f32)
  char* wsb = (char*)d_ws;
  float* ws_s = (float*)wsb;
  unsigned char* ws_z = (unsigned char*)(wsb + 20971520);
  float* Wexp = (float*)(wsb + 26992640);
  float* S2   = (float*)(wsb + 34529280);

  k_expand<<<dim3(7360), dim3(256), 0, stream>>>(dec2_w, Wexp);
  k_enc<<<dim3(4096), dim3(256), 0, stream>>>(
      x, enc1_w, pw1, pw2, enc2_w, h_w, h_b, mean_w, mean_b, lv_w, lv_b,
      o_mean, o_lv, o_eta, ws_s, ws_z);
  k_gemm<<<dim3(23, 32), dim3(256), 0, stream>>>(ws_s, Wexp, S2);
  k_unpool<<<dim3(4096), dim3(256), 0, stream>>>(S2, ws_z, dec1_w, alpha, o_xrec);
}

// Round 2
// 1963.592 us; speedup vs baseline: 1.9259x; 1.2862x over previous
//
#include <hip/hip_runtime.h>
#include <cstdint>

// ---------------------------------------------------------------------------
// DGDN forward (B=4096). Outputs (f32, concat): x_rec[4096,1,28,28],
// mean[4096,80,16], log_var[4096,80,16], eta[4096,30,7,7,9].
// RNG: JAX threefry2x32, jax_threefry_partitionable=True reconstruction.
// k_enc restructured: wave-per-channel conv (broadcast weights, register
// sliding window), enc2 with patch-in-regs + global-direct weights (no LDS
// staging, no bank conflicts). Accumulation order per output unchanged.
// ---------------------------------------------------------------------------

#define OFF_MEAN 3211264
#define OFF_LV   8454144
#define OFF_ETA  13697024

// ------------------------- threefry2x32 (constexpr) ------------------------
constexpr uint64_t ctf(uint32_t k0, uint32_t k1, uint32_t x0, uint32_t x1) {
  uint32_t ks0 = k0, ks1 = k1, ks2 = k0 ^ k1 ^ 0x1BD11BDAu;
  const int rotA[4] = {13, 15, 26, 6};
  const int rotB[4] = {17, 29, 16, 24};
  x0 += ks0; x1 += ks1;
  for (int g = 0; g < 5; ++g) {
    for (int i = 0; i < 4; ++i) {
      int r = (g & 1) ? rotB[i] : rotA[i];
      x0 += x1;
      x1 = (uint32_t)((x1 << r) | (x1 >> (32 - r)));
      x1 ^= x0;
    }
    uint32_t ka = (g + 1) % 3 == 0 ? ks0 : ((g + 1) % 3 == 1 ? ks1 : ks2);
    uint32_t kb = (g + 2) % 3 == 0 ? ks0 : ((g + 2) % 3 == 1 ? ks1 : ks2);
    x0 += ka;
    x1 += kb + (uint32_t)(g + 1);
  }
  return ((uint64_t)x0 << 32) | (uint64_t)x1;
}

constexpr uint64_t KP_ = ctf(0u, 42u, 0u, 0u);  // k_pool
constexpr uint64_t KU_ = ctf(0u, 42u, 0u, 1u);  // k_unpool
constexpr uint64_t KC_ = ctf(0u, 42u, 0u, 2u);  // k_code
constexpr uint64_t KN_ = ctf(0u, 42u, 0u, 3u);  // k_noise
constexpr uint32_t KPOOL0 = (uint32_t)(KP_ >> 32), KPOOL1 = (uint32_t)KP_;
constexpr uint32_t KUNP0  = (uint32_t)(KU_ >> 32), KUNP1  = (uint32_t)KU_;
constexpr uint32_t KCODE0 = (uint32_t)(KC_ >> 32), KCODE1 = (uint32_t)KC_;
constexpr uint32_t KNOIS0 = (uint32_t)(KN_ >> 32), KNOIS1 = (uint32_t)KN_;

// ------------------------- device threefry + draws -------------------------
__device__ __forceinline__ uint2 tf_dev(uint32_t k0, uint32_t k1, uint32_t x0, uint32_t x1) {
  uint32_t ks2 = k0 ^ k1 ^ 0x1BD11BDAu;
  x0 += k0; x1 += k1;
#define TFR(r) { x0 += x1; x1 = (x1 << (r)) | (x1 >> (32 - (r))); x1 ^= x0; }
  TFR(13) TFR(15) TFR(26) TFR(6)
  x0 += k1;  x1 += ks2 + 1u;
  TFR(17) TFR(29) TFR(16) TFR(24)
  x0 += ks2; x1 += k0 + 2u;
  TFR(13) TFR(15) TFR(26) TFR(6)
  x0 += k0;  x1 += k1 + 3u;
  TFR(17) TFR(29) TFR(16) TFR(24)
  x0 += k1;  x1 += ks2 + 4u;
  TFR(13) TFR(15) TFR(26) TFR(6)
  x0 += ks2; x1 += k0 + 5u;
#undef TFR
  return make_uint2(x0, x1);
}

__device__ __forceinline__ uint32_t rbits32(uint32_t k0, uint32_t k1, uint32_t idx) {
  uint2 r = tf_dev(k0, k1, 0u, idx);
  return r.x ^ r.y;
}

__device__ __forceinline__ float u01_from_bits(uint32_t bits) {
  return __uint_as_float((bits >> 9) | 0x3F800000u) - 1.0f;
}

__device__ __forceinline__ float gumbel_draw(uint32_t k0, uint32_t k1, uint32_t idx) {
  float u01 = u01_from_bits(rbits32(k0, k1, idx));
  float u = fmaxf(__fadd_rn(u01, 1.17549435e-38f), 1.17549435e-38f);
  return -logf(-logf(u));
}

__device__ __forceinline__ float erfinv_xla(float x) {
  float t = __fmul_rn(x, x);
  float w = -log1pf(-t);
  float p;
  if (w < 5.0f) {
    w = __fadd_rn(w, -2.5f);
    p = 2.81022636e-08f;
    p = __fadd_rn(__fmul_rn(p, w), 3.43273939e-07f);
    p = __fadd_rn(__fmul_rn(p, w), -3.5233877e-06f);
    p = __fadd_rn(__fmul_rn(p, w), -4.39150654e-06f);
    p = __fadd_rn(__fmul_rn(p, w), 0.00021858087f);
    p = __fadd_rn(__fmul_rn(p, w), -0.00125372503f);
    p = __fadd_rn(__fmul_rn(p, w), -0.00417768164f);
    p = __fadd_rn(__fmul_rn(p, w), 0.246640727f);
    p = __fadd_rn(__fmul_rn(p, w), 1.50140941f);
  } else {
    w = __fadd_rn(sqrtf(w), -3.0f);
    p = -0.000200214257f;
    p = __fadd_rn(__fmul_rn(p, w), 0.000100950558f);
    p = __fadd_rn(__fmul_rn(p, w), 0.00134934322f);
    p = __fadd_rn(__fmul_rn(p, w), -0.00367342844f);
    p = __fadd_rn(__fmul_rn(p, w), 0.00573950773f);
    p = __fadd_rn(__fmul_rn(p, w), -0.0076224613f);
    p = __fadd_rn(__fmul_rn(p, w), 0.00943887047f);
    p = __fadd_rn(__fmul_rn(p, w), 1.00167406f);
    p = __fadd_rn(__fmul_rn(p, w), 2.83297682f);
  }
  return __fmul_rn(p, x);
}

__device__ __forceinline__ float normal_draw(uint32_t k0, uint32_t k1, uint32_t idx) {
  float u01 = u01_from_bits(rbits32(k0, k1, idx));
  float u = fmaxf(__fadd_rn(__fmul_rn(u01, 2.0f), -0.99999994f), -0.99999994f);
  return __fmul_rn(1.41421356237309515f, erfinv_xla(u));
}

__device__ __forceinline__ float tanh_xla(float x) {
  float ax = fabsf(x);
  float xc = fmaxf(fminf(x, 7.90531110763549805f), -7.90531110763549805f);
  float x2 = __fmul_rn(xc, xc);
  float p = __fmaf_rn(x2, -2.76076847742355e-16f, 2.00018790482477e-13f);
  p = __fmaf_rn(x2, p, -8.60467152213735e-11f);
  p = __fmaf_rn(x2, p, 5.12229709037114e-08f);
  p = __fmaf_rn(x2, p, 1.48572235717979e-05f);
  p = __fmaf_rn(x2, p, 6.37261928875436e-04f);
  p = __fmaf_rn(x2, p, 4.89352455891786e-03f);
  p = __fmul_rn(xc, p);
  float q = __fmaf_rn(x2, 1.19825839466702e-06f, 1.18534705686654e-04f);
  q = __fmaf_rn(x2, q, 2.26843463243900e-03f);
  q = __fmaf_rn(x2, q, 4.89352518554385e-03f);
  return (ax < 0.0004f) ? x : __fdiv_rn(p, q);
}

// ---------------------------------------------------------------------------
// Encoder. Per-output accumulation order is IDENTICAL to the previous
// (verified) kernel: conv1 per output (p,q): dy asc, dx asc; enc2: c asc,
// dy asc, dx asc; MLPs: i asc. Only data movement / thread mapping changed.
// ---------------------------------------------------------------------------
__global__ __launch_bounds__(256) void k_enc(
    const float* __restrict__ x, const float* __restrict__ enc1_w,
    const float* __restrict__ pw1, const float* __restrict__ pw2,
    const float* __restrict__ enc2_w, const float* __restrict__ h_w,
    const float* __restrict__ h_b, const float* __restrict__ mean_w,
    const float* __restrict__ mean_b, const float* __restrict__ lv_w,
    const float* __restrict__ lv_b,
    float* __restrict__ o_mean, float* __restrict__ o_lv, float* __restrict__ o_eta,
    float* __restrict__ ws_s, unsigned char* __restrict__ ws_z) {
  __shared__ float lds[2866];      // phase1: xs(784)|w1s(1920)|pp1(81)|pp2(81)
                                   // phase2: c2s(1280)|hs(1280) overlay
  __shared__ float pooled[1470];
  const int b = blockIdx.x, tid = threadIdx.x;
  const int wv = tid >> 6, lane = tid & 63;

  float* xs  = lds;
  float* w1s = lds + 784;
  float* pp1 = lds + 2704;
  float* pp2 = lds + 2785;
  for (int i = tid; i < 784; i += 256) xs[i] = x[(size_t)b * 784 + i];
  for (int i = tid; i < 1920; i += 256) w1s[i] = enc1_w[i];
  if (tid < 81) { pp1[tid] = pw1[tid]; pp2[tid] = pw2[tid]; }
  __syncthreads();

  // ---- phase 1: conv1 + pooling MLP + eta + zeta draws -----------------
  // wave wv handles channels {wv, wv+4, ...}; lane = cell (49 active).
  for (int c = wv; c < 30; c += 4) {
    const float* wc = &w1s[c * 64];
    if (lane < 49) {
      const int n = lane / 7, m = lane - n * 7;
      const int yb = n * 3, xb = m * 3;

      // register sliding window of 3 input rows x 10 cols
      float R[3][10];
#pragma unroll
      for (int rr = 0; rr < 3; ++rr)
#pragma unroll
        for (int i = 0; i < 10; ++i) R[rr][i] = xs[(yb + rr) * 28 + xb + i];

      float tile[9];
#pragma unroll
      for (int i = 0; i < 9; ++i) tile[i] = 0.f;

#pragma unroll
      for (int dy = 0; dy < 8; ++dy) {
        float4 wa = *(const float4*)&wc[dy * 8];
        float4 wb = *(const float4*)&wc[dy * 8 + 4];
        float w8[8] = {wa.x, wa.y, wa.z, wa.w, wb.x, wb.y, wb.z, wb.w};
#pragma unroll
        for (int dx = 0; dx < 8; ++dx) {
          float w = w8[dx];
#pragma unroll
          for (int p = 0; p < 3; ++p)
#pragma unroll
            for (int q = 0; q < 3; ++q)
              tile[p * 3 + q] = __fmaf_rn(R[(dy + p) % 3][dx + q], w, tile[p * 3 + q]);
        }
        if (dy < 7) {
#pragma unroll
          for (int i = 0; i < 10; ++i) R[dy % 3][i] = xs[(yb + dy + 3) * 28 + xb + i];
        }
      }

      // pooling MLP + softmax + eta + gumbel argmax (identical arithmetic)
      float h1v[9];
#pragma unroll
      for (int o = 0; o < 9; ++o) {
        float a = 0.f;
#pragma unroll
        for (int t = 0; t < 9; ++t) a += tile[t] * pp1[o * 9 + t];
        h1v[o] = tanh_xla(a);
      }
      float lg[9], mx = -3.4e38f;
#pragma unroll
      for (int o = 0; o < 9; ++o) {
        float a = 0.f;
#pragma unroll
        for (int t = 0; t < 9; ++t) a += h1v[t] * pp2[o * 9 + t];
        lg[o] = a;
        mx = fmaxf(mx, a);
      }
      float ev[9], ssum = 0.f;
#pragma unroll
      for (int o = 0; o < 9; ++o) { ev[o] = expf(__fadd_rn(lg[o], -mx)); ssum += ev[o]; }
      float leta[9];
      size_t ebase = ((size_t)(b * 30 + c) * 49 + lane) * 9;
#pragma unroll
      for (int o = 0; o < 9; ++o) {
        float e = __fdiv_rn(ev[o], ssum);
        o_eta[ebase + o] = e;
        leta[o] = logf(e);
      }
      uint32_t fb = (uint32_t)ebase;
      float best1 = -3.4e38f, best2 = -3.4e38f, pooledv = 0.f;
      int z2 = 0;
#pragma unroll
      for (int t = 0; t < 9; ++t) {
        float v1 = __fadd_rn(leta[t], gumbel_draw(KPOOL0, KPOOL1, fb + t));
        bool t1 = v1 > best1; best1 = t1 ? v1 : best1; pooledv = t1 ? tile[t] : pooledv;
        float v2 = __fadd_rn(leta[t], gumbel_draw(KUNP0, KUNP1, fb + t));
        bool t2 = v2 > best2; best2 = t2 ? v2 : best2; z2 = t2 ? t : z2;
      }
      pooled[c * 49 + lane] = pooledv;
      ws_z[(size_t)b * 1470 + c * 49 + lane] = (unsigned char)z2;
    }
  }
  __syncthreads();

  // ---- phase 2: enc2 (4x4 conv over pooled) ----------------------------
  // thread = (k2l, pos); acc[5] over k2 groups; patch row loaded once per c
  // (shared by all 5 outputs); weights streamed from global (L2-resident).
  float* c2s = lds;          // 1280, overlays xs/w1s (safe after barrier)
  float* hs  = lds + 1280;   // 1280
  const int k2l = tid >> 4, pos = tid & 15;
  const int uy = pos >> 2, ux = pos & 3;
  {
    float acc[5] = {0.f, 0.f, 0.f, 0.f, 0.f};
    for (int c = 0; c < 30; ++c) {
      float pr[16];
#pragma unroll
      for (int dy = 0; dy < 4; ++dy)
#pragma unroll
        for (int dx = 0; dx < 4; ++dx)
          pr[dy * 4 + dx] = pooled[c * 49 + (uy + dy) * 7 + ux + dx];
#pragma unroll
      for (int j = 0; j < 5; ++j) {
        const float4* wr = (const float4*)&enc2_w[(size_t)((j * 16 + k2l) * 30 + c) * 16];
        float4 w0 = wr[0], w1 = wr[1], w2 = wr[2], w3 = wr[3];
        float a = acc[j];
        a = __fmaf_rn(pr[0],  w0.x, a);  a = __fmaf_rn(pr[1],  w0.y, a);
        a = __fmaf_rn(pr[2],  w0.z, a);  a = __fmaf_rn(pr[3],  w0.w, a);
        a = __fmaf_rn(pr[4],  w1.x, a);  a = __fmaf_rn(pr[5],  w1.y, a);
        a = __fmaf_rn(pr[6],  w1.z, a);  a = __fmaf_rn(pr[7],  w1.w, a);
        a = __fmaf_rn(pr[8],  w2.x, a);  a = __fmaf_rn(pr[9],  w2.y, a);
        a = __fmaf_rn(pr[10], w2.z, a);  a = __fmaf_rn(pr[11], w2.w, a);
        a = __fmaf_rn(pr[12], w3.x, a);  a = __fmaf_rn(pr[13], w3.y, a);
        a = __fmaf_rn(pr[14], w3.z, a);  a = __fmaf_rn(pr[15], w3.w, a);
        acc[j] = a;
      }
    }
#pragma unroll
    for (int j = 0; j < 5; ++j) c2s[(j * 16 + k2l) * 16 + pos] = acc[j];
  }
  __syncthreads();

  // ---- phase 3: per-channel code MLPs ----------------------------------
#pragma unroll
  for (int j = 0; j < 5; ++j) {
    int it = tid + j * 256;
    int k2 = it >> 4;
    const float4* wr4 = (const float4*)&h_w[(size_t)it * 16];
    float4 a0 = wr4[0], a1 = wr4[1], a2 = wr4[2], a3 = wr4[3];
    float wv16[16] = {a0.x, a0.y, a0.z, a0.w, a1.x, a1.y, a1.z, a1.w,
                      a2.x, a2.y, a2.z, a2.w, a3.x, a3.y, a3.z, a3.w};
    float d = 0.f;
#pragma unroll
    for (int i = 0; i < 16; ++i) d += c2s[k2 * 16 + i] * wv16[i];
    hs[it] = tanh_xla(__fadd_rn(d, h_b[it]));
  }
  __syncthreads();

#pragma unroll
  for (int j = 0; j < 5; ++j) {
    int it = tid + j * 256;
    int k2 = it >> 4;
    const float4* wm4 = (const float4*)&mean_w[(size_t)it * 16];
    const float4* wl4 = (const float4*)&lv_w[(size_t)it * 16];
    float4 m0 = wm4[0], m1 = wm4[1], m2 = wm4[2], m3 = wm4[3];
    float4 l0 = wl4[0], l1 = wl4[1], l2 = wl4[2], l3 = wl4[3];
    float wm16[16] = {m0.x, m0.y, m0.z, m0.w, m1.x, m1.y, m1.z, m1.w,
                      m2.x, m2.y, m2.z, m2.w, m3.x, m3.y, m3.z, m3.w};
    float wl16[16] = {l0.x, l0.y, l0.z, l0.w, l1.x, l1.y, l1.z, l1.w,
                      l2.x, l2.y, l2.z, l2.w, l3.x, l3.y, l3.z, l3.w};
    float dm = 0.f, dl = 0.f;
#pragma unroll
    for (int i = 0; i < 16; ++i) {
      float hv = hs[k2 * 16 + i];
      dm += hv * wm16[i];
      dl += hv * wl16[i];
    }
    float mean = __fadd_rn(dm, mean_b[it]);
    float lv = __fadd_rn(dl, lv_b[it]);
    size_t gi = (size_t)b * 1280 + it;
    o_mean[gi] = mean;
    o_lv[gi] = lv;
    float stdv = expf(__fmul_rn(0.5f, lv));
    float z = normal_draw(KCODE0, KCODE1, (uint32_t)(b * 1280 + it));
    ws_s[gi] = __fadd_rn(mean, __fmul_rn(stdv, z));
  }
}

// ---------------------------------------------------------------------------
// k_expand: Wexp[k=1280][t=1472] from dec2_w.
// ---------------------------------------------------------------------------
__global__ __launch_bounds__(256) void k_expand(const float* __restrict__ dec2_w,
                                                float* __restrict__ Wexp) {
  int idx = blockIdx.x * 256 + threadIdx.x;       // < 1280*1472
  int k = idx / 1472, t = idx - k * 1472;
  int k2 = k >> 4, iy = (k >> 2) & 3, ix = k & 3;
  int c = t / 49, cell = t - c * 49;
  int u = cell / 7, v = cell - u * 7;
  int du = u - iy, dv = v - ix;
  float val = 0.f;
  if (t < 1470 && (unsigned)du < 4u && (unsigned)dv < 4u)
    val = dec2_w[((k2 * 30 + c) << 4) + (du << 2) + dv];
  Wexp[idx] = val;
}

// ---------------------------------------------------------------------------
// k_gemm: S2[4096,1472] = A[4096,1280] x Wexp[1280,1472]
// ---------------------------------------------------------------------------
__global__ __launch_bounds__(256) void k_gemm(const float* __restrict__ A,
                                              const float* __restrict__ Bm,
                                              float* __restrict__ C) {
  __shared__ float As[16][132];
  __shared__ float Bs[16][64];
  const int tid = threadIdx.x;
  const int n0 = blockIdx.x * 64;
  const int m0 = blockIdx.y * 128;
  const int tx = tid & 15, ty = tid >> 4;

  float acc[8][4];
#pragma unroll
  for (int i = 0; i < 8; ++i)
#pragma unroll
    for (int j = 0; j < 4; ++j) acc[i][j] = 0.f;

  const int fa_r0 = tid >> 2, fa_c = (tid & 3) << 2;
  const int fb_k = tid >> 4, fb_c = (tid & 15) << 2;

  for (int k0 = 0; k0 < 1280; k0 += 16) {
    __syncthreads();
    float4 a0 = *(const float4*)&A[(size_t)(m0 + fa_r0) * 1280 + k0 + fa_c];
    float4 a1 = *(const float4*)&A[(size_t)(m0 + 64 + fa_r0) * 1280 + k0 + fa_c];
    float4 bv = *(const float4*)&Bm[(size_t)(k0 + fb_k) * 1472 + n0 + fb_c];
    As[fa_c + 0][fa_r0] = a0.x;  As[fa_c + 1][fa_r0] = a0.y;
    As[fa_c + 2][fa_r0] = a0.z;  As[fa_c + 3][fa_r0] = a0.w;
    As[fa_c + 0][64 + fa_r0] = a1.x;  As[fa_c + 1][64 + fa_r0] = a1.y;
    As[fa_c + 2][64 + fa_r0] = a1.z;  As[fa_c + 3][64 + fa_r0] = a1.w;
    *(float4*)&Bs[fb_k][fb_c] = bv;
    __syncthreads();

#pragma unroll
    for (int kk = 0; kk < 16; ++kk) {
      float4 av0 = *(const float4*)&As[kk][ty * 8];
      float4 av1 = *(const float4*)&As[kk][ty * 8 + 4];
      float4 bv0 = *(const float4*)&Bs[kk][tx * 4];
      float am[8] = {av0.x, av0.y, av0.z, av0.w, av1.x, av1.y, av1.z, av1.w};
      float bn[4] = {bv0.x, bv0.y, bv0.z, bv0.w};
#pragma unroll
      for (int i = 0; i < 8; ++i)
#pragma unroll
        for (int j = 0; j < 4; ++j) acc[i][j] = __fmaf_rn(am[i], bn[j], acc[i][j]);
    }
  }

#pragma unroll
  for (int i = 0; i < 8; ++i) {
    size_t row = (size_t)(m0 + ty * 8 + i);
    float4 o = make_float4(acc[i][0], acc[i][1], acc[i][2], acc[i][3]);
    *(float4*)&C[row * 1472 + n0 + tx * 4] = o;
  }
}

// ---------------------------------------------------------------------------
// k_unpool (gather, no atomics).
// ---------------------------------------------------------------------------
__global__ __launch_bounds__(256) void k_unpool(
    const float* __restrict__ S2, const unsigned char* __restrict__ ws_z,
    const float* __restrict__ dec1_w, const float* __restrict__ alpha,
    float* __restrict__ o_xrec) {
  __shared__ float w1s[1920];
  __shared__ float vals[1470];
  __shared__ unsigned short pyx[1470];
  const int b = blockIdx.x, tid = threadIdx.x;

  for (int i = tid; i < 1920; i += 256) w1s[i] = dec1_w[i];
#pragma unroll
  for (int j = 0; j < 6; ++j) {
    int t = tid + j * 256;
    if (t < 1470) {
      int c = t / 49, cell = t - c * 49;
      int n = cell / 7, m = cell - n * 7;
      int z = ws_z[(size_t)b * 1470 + t];
      int p = z / 3, q = z - p * 3;
      vals[t] = S2[(size_t)b * 1472 + t];
      pyx[t] = (unsigned short)((n * 3 + p) | ((m * 3 + q) << 5));
    }
  }
  __syncthreads();

  float inva = __fdiv_rn(1.0f, alpha[0]);
  for (int pix = tid; pix < 784; pix += 256) {
    int y = pix / 28, x = pix - y * 28;
    int nlo = (y >= 9) ? ((y - 9 + 2) / 3) : 0;
    int nhi = min(6, y / 3);
    int mlo = (x >= 9) ? ((x - 9 + 2) / 3) : 0;
    int mhi = min(6, x / 3);

    float acc = 0.f;
    for (int c = 0; c < 30; ++c) {
      const int cbase = c * 49;
      const float* wc = &w1s[c * 64];
      for (int n = nlo; n <= nhi; ++n) {
        const int t0 = cbase + n * 7;
#pragma unroll 4
        for (int m = mlo; m <= mhi; ++m) {
          int t = t0 + m;
          int pp = pyx[t];
          int dy = y - (pp & 31);
          int dx = x - (pp >> 5);
          bool ok = ((unsigned)dy < 8u) & ((unsigned)dx < 8u);
          float wvv = wc[((dy & 7) << 3) + (dx & 7)];
          float vv = ok ? vals[t] : 0.f;
          acc = __fmaf_rn(vv, wvv, acc);
        }
      }
    }
    if (y == x) {
      float zn = normal_draw(KNOIS0, KNOIS1, (uint32_t)(b * 784 + pix));
      acc = __fadd_rn(acc, __fmul_rn(inva, zn));
    }
    o_xrec[(size_t)b * 784 + pix] = acc;
  }
}

// ---------------------------------------------------------------------------
extern "C" void kernel_launch(void* const* d_in, const int* in_sizes, int n_in,
                              void* d_out, int out_size, void* d_ws, size_t ws_size,
                              hipStream_t stream) {
  const float* x      = (const float*)d_in[0];
  const float* enc1_w = (const float*)d_in[1];
  const float* pw1    = (const float*)d_in[2];
  const float* pw2    = (const float*)d_in[3];
  const float* enc2_w = (const float*)d_in[4];
  const float* h_w    = (const float*)d_in[5];
  const float* h_b    = (const float*)d_in[6];
  const float* mean_w = (const float*)d_in[7];
  const float* mean_b = (const float*)d_in[8];
  const float* lv_w   = (const float*)d_in[9];
  const float* lv_b   = (const float*)d_in[10];
  const float* dec2_w = (const float*)d_in[11];
  const float* dec1_w = (const float*)d_in[12];
  const float* alpha  = (const float*)d_in[13];

  float* out = (float*)d_out;
  float* o_xrec = out;
  float* o_mean = out + OFF_MEAN;
  float* o_lv   = out + OFF_LV;
  float* o_eta  = out + OFF_ETA;

  char* wsb = (char*)d_ws;
  float* ws_s = (float*)wsb;
  unsigned char* ws_z = (unsigned char*)(wsb + 20971520);
  float* Wexp = (float*)(wsb + 26992640);
  float* S2   = (float*)(wsb + 34529280);

  k_expand<<<dim3(7360), dim3(256), 0, stream>>>(dec2_w, Wexp);
  k_enc<<<dim3(4096), dim3(256), 0, stream>>>(
      x, enc1_w, pw1, pw2, enc2_w, h_w, h_b, mean_w, mean_b, lv_w, lv_b,
      o_mean, o_lv, o_eta, ws_s, ws_z);
  k_gemm<<<dim3(23, 32), dim3(256), 0, stream>>>(ws_s, Wexp, S2);
  k_unpool<<<dim3(4096), dim3(256), 0, stream>>>(S2, ws_z, dec1_w, alpha, o_xrec);
}

// Round 3
// 1690.247 us; speedup vs baseline: 2.2373x; 1.1617x over previous
//
#include <hip/hip_runtime.h>
#include <cstdint>

// ---------------------------------------------------------------------------
// DGDN forward (B=4096). Outputs (f32, concat): x_rec[4096,1,28,28],
// mean[4096,80,16], log_var[4096,80,16], eta[4096,30,7,7,9].
// RNG: JAX threefry2x32, jax_threefry_partitionable=True reconstruction.
// R3: k_enc phase1 full-lane flat mapping (95.7% util vs 76.6%);
//     k_unpool fixed 4x4 predicated window, fully unrolled, b64-packed LDS.
// ---------------------------------------------------------------------------

#define OFF_MEAN 3211264
#define OFF_LV   8454144
#define OFF_ETA  13697024

// ------------------------- threefry2x32 (constexpr) ------------------------
constexpr uint64_t ctf(uint32_t k0, uint32_t k1, uint32_t x0, uint32_t x1) {
  uint32_t ks0 = k0, ks1 = k1, ks2 = k0 ^ k1 ^ 0x1BD11BDAu;
  const int rotA[4] = {13, 15, 26, 6};
  const int rotB[4] = {17, 29, 16, 24};
  x0 += ks0; x1 += ks1;
  for (int g = 0; g < 5; ++g) {
    for (int i = 0; i < 4; ++i) {
      int r = (g & 1) ? rotB[i] : rotA[i];
      x0 += x1;
      x1 = (uint32_t)((x1 << r) | (x1 >> (32 - r)));
      x1 ^= x0;
    }
    uint32_t ka = (g + 1) % 3 == 0 ? ks0 : ((g + 1) % 3 == 1 ? ks1 : ks2);
    uint32_t kb = (g + 2) % 3 == 0 ? ks0 : ((g + 2) % 3 == 1 ? ks1 : ks2);
    x0 += ka;
    x1 += kb + (uint32_t)(g + 1);
  }
  return ((uint64_t)x0 << 32) | (uint64_t)x1;
}

constexpr uint64_t KP_ = ctf(0u, 42u, 0u, 0u);  // k_pool
constexpr uint64_t KU_ = ctf(0u, 42u, 0u, 1u);  // k_unpool
constexpr uint64_t KC_ = ctf(0u, 42u, 0u, 2u);  // k_code
constexpr uint64_t KN_ = ctf(0u, 42u, 0u, 3u);  // k_noise
constexpr uint32_t KPOOL0 = (uint32_t)(KP_ >> 32), KPOOL1 = (uint32_t)KP_;
constexpr uint32_t KUNP0  = (uint32_t)(KU_ >> 32), KUNP1  = (uint32_t)KU_;
constexpr uint32_t KCODE0 = (uint32_t)(KC_ >> 32), KCODE1 = (uint32_t)KC_;
constexpr uint32_t KNOIS0 = (uint32_t)(KN_ >> 32), KNOIS1 = (uint32_t)KN_;

// ------------------------- device threefry + draws -------------------------
__device__ __forceinline__ uint2 tf_dev(uint32_t k0, uint32_t k1, uint32_t x0, uint32_t x1) {
  uint32_t ks2 = k0 ^ k1 ^ 0x1BD11BDAu;
  x0 += k0; x1 += k1;
#define TFR(r) { x0 += x1; x1 = (x1 << (r)) | (x1 >> (32 - (r))); x1 ^= x0; }
  TFR(13) TFR(15) TFR(26) TFR(6)
  x0 += k1;  x1 += ks2 + 1u;
  TFR(17) TFR(29) TFR(16) TFR(24)
  x0 += ks2; x1 += k0 + 2u;
  TFR(13) TFR(15) TFR(26) TFR(6)
  x0 += k0;  x1 += k1 + 3u;
  TFR(17) TFR(29) TFR(16) TFR(24)
  x0 += k1;  x1 += ks2 + 4u;
  TFR(13) TFR(15) TFR(26) TFR(6)
  x0 += ks2; x1 += k0 + 5u;
#undef TFR
  return make_uint2(x0, x1);
}

__device__ __forceinline__ uint32_t rbits32(uint32_t k0, uint32_t k1, uint32_t idx) {
  uint2 r = tf_dev(k0, k1, 0u, idx);
  return r.x ^ r.y;
}

__device__ __forceinline__ float u01_from_bits(uint32_t bits) {
  return __uint_as_float((bits >> 9) | 0x3F800000u) - 1.0f;
}

__device__ __forceinline__ float gumbel_draw(uint32_t k0, uint32_t k1, uint32_t idx) {
  float u01 = u01_from_bits(rbits32(k0, k1, idx));
  float u = fmaxf(__fadd_rn(u01, 1.17549435e-38f), 1.17549435e-38f);
  return -logf(-logf(u));
}

__device__ __forceinline__ float erfinv_xla(float x) {
  float t = __fmul_rn(x, x);
  float w = -log1pf(-t);
  float p;
  if (w < 5.0f) {
    w = __fadd_rn(w, -2.5f);
    p = 2.81022636e-08f;
    p = __fadd_rn(__fmul_rn(p, w), 3.43273939e-07f);
    p = __fadd_rn(__fmul_rn(p, w), -3.5233877e-06f);
    p = __fadd_rn(__fmul_rn(p, w), -4.39150654e-06f);
    p = __fadd_rn(__fmul_rn(p, w), 0.00021858087f);
    p = __fadd_rn(__fmul_rn(p, w), -0.00125372503f);
    p = __fadd_rn(__fmul_rn(p, w), -0.00417768164f);
    p = __fadd_rn(__fmul_rn(p, w), 0.246640727f);
    p = __fadd_rn(__fmul_rn(p, w), 1.50140941f);
  } else {
    w = __fadd_rn(sqrtf(w), -3.0f);
    p = -0.000200214257f;
    p = __fadd_rn(__fmul_rn(p, w), 0.000100950558f);
    p = __fadd_rn(__fmul_rn(p, w), 0.00134934322f);
    p = __fadd_rn(__fmul_rn(p, w), -0.00367342844f);
    p = __fadd_rn(__fmul_rn(p, w), 0.00573950773f);
    p = __fadd_rn(__fmul_rn(p, w), -0.0076224613f);
    p = __fadd_rn(__fmul_rn(p, w), 0.00943887047f);
    p = __fadd_rn(__fmul_rn(p, w), 1.00167406f);
    p = __fadd_rn(__fmul_rn(p, w), 2.83297682f);
  }
  return __fmul_rn(p, x);
}

__device__ __forceinline__ float normal_draw(uint32_t k0, uint32_t k1, uint32_t idx) {
  float u01 = u01_from_bits(rbits32(k0, k1, idx));
  float u = fmaxf(__fadd_rn(__fmul_rn(u01, 2.0f), -0.99999994f), -0.99999994f);
  return __fmul_rn(1.41421356237309515f, erfinv_xla(u));
}

__device__ __forceinline__ float tanh_xla(float x) {
  float ax = fabsf(x);
  float xc = fmaxf(fminf(x, 7.90531110763549805f), -7.90531110763549805f);
  float x2 = __fmul_rn(xc, xc);
  float p = __fmaf_rn(x2, -2.76076847742355e-16f, 2.00018790482477e-13f);
  p = __fmaf_rn(x2, p, -8.60467152213735e-11f);
  p = __fmaf_rn(x2, p, 5.12229709037114e-08f);
  p = __fmaf_rn(x2, p, 1.48572235717979e-05f);
  p = __fmaf_rn(x2, p, 6.37261928875436e-04f);
  p = __fmaf_rn(x2, p, 4.89352455891786e-03f);
  p = __fmul_rn(xc, p);
  float q = __fmaf_rn(x2, 1.19825839466702e-06f, 1.18534705686654e-04f);
  q = __fmaf_rn(x2, q, 2.26843463243900e-03f);
  q = __fmaf_rn(x2, q, 4.89352518554385e-03f);
  return (ax < 0.0004f) ? x : __fdiv_rn(p, q);
}

// ---------------------------------------------------------------------------
// Encoder. Per-output accumulation order is IDENTICAL to the verified kernel:
// conv1 per output (p,q): dy asc, dx asc; enc2: c asc, dy asc, dx asc;
// MLPs: i asc. Only thread mapping / data movement changed.
// ---------------------------------------------------------------------------
__global__ __launch_bounds__(256) void k_enc(
    const float* __restrict__ x, const float* __restrict__ enc1_w,
    const float* __restrict__ pw1, const float* __restrict__ pw2,
    const float* __restrict__ enc2_w, const float* __restrict__ h_w,
    const float* __restrict__ h_b, const float* __restrict__ mean_w,
    const float* __restrict__ mean_b, const float* __restrict__ lv_w,
    const float* __restrict__ lv_b,
    float* __restrict__ o_mean, float* __restrict__ o_lv, float* __restrict__ o_eta,
    float* __restrict__ ws_s, unsigned char* __restrict__ ws_z) {
  __shared__ float lds[2866];      // phase1: xs(784)|w1s(1920)|pp1(81)|pp2(81)
                                   // phase2: c2s(1280)|hs(1280) overlay
  __shared__ float pooled[1470];
  const int b = blockIdx.x, tid = threadIdx.x;

  float* xs  = lds;
  float* w1s = lds + 784;
  float* pp1 = lds + 2704;
  float* pp2 = lds + 2785;
  for (int i = tid; i < 784; i += 256) xs[i] = x[(size_t)b * 784 + i];
  for (int i = tid; i < 1920; i += 256) w1s[i] = enc1_w[i];
  if (tid < 81) { pp1[tid] = pw1[tid]; pp2[tid] = pw2[tid]; }
  __syncthreads();

  // ---- phase 1: conv1 + pooling MLP + eta + zeta draws -----------------
  // flat mapping: g = c*49+cell over all 256 lanes (95.7% utilization);
  // per-wave weight reads hit <=2 distinct LDS addresses (2-way = free).
  for (int g = tid; g < 1470; g += 256) {
    const int c = g / 49, cell = g - c * 49;
    const int n = cell / 7, m = cell - n * 7;
    const int yb = n * 3, xb = m * 3;
    const float* wc = &w1s[c * 64];

    // register sliding window of 3 input rows x 10 cols
    float R[3][10];
#pragma unroll
    for (int rr = 0; rr < 3; ++rr)
#pragma unroll
      for (int i = 0; i < 10; ++i) R[rr][i] = xs[(yb + rr) * 28 + xb + i];

    float tile[9];
#pragma unroll
    for (int i = 0; i < 9; ++i) tile[i] = 0.f;

#pragma unroll
    for (int dy = 0; dy < 8; ++dy) {
      float4 wa = *(const float4*)&wc[dy * 8];
      float4 wb = *(const float4*)&wc[dy * 8 + 4];
      float w8[8] = {wa.x, wa.y, wa.z, wa.w, wb.x, wb.y, wb.z, wb.w};
#pragma unroll
      for (int dx = 0; dx < 8; ++dx) {
        float w = w8[dx];
#pragma unroll
        for (int p = 0; p < 3; ++p)
#pragma unroll
          for (int q = 0; q < 3; ++q)
            tile[p * 3 + q] = __fmaf_rn(R[(dy + p) % 3][dx + q], w, tile[p * 3 + q]);
      }
      if (dy < 7) {
#pragma unroll
        for (int i = 0; i < 10; ++i) R[dy % 3][i] = xs[(yb + dy + 3) * 28 + xb + i];
      }
    }

    // pooling MLP + softmax + eta + gumbel argmax (identical arithmetic)
    float h1v[9];
#pragma unroll
    for (int o = 0; o < 9; ++o) {
      float a = 0.f;
#pragma unroll
      for (int t = 0; t < 9; ++t) a += tile[t] * pp1[o * 9 + t];
      h1v[o] = tanh_xla(a);
    }
    float lg[9], mx = -3.4e38f;
#pragma unroll
    for (int o = 0; o < 9; ++o) {
      float a = 0.f;
#pragma unroll
      for (int t = 0; t < 9; ++t) a += h1v[t] * pp2[o * 9 + t];
      lg[o] = a;
      mx = fmaxf(mx, a);
    }
    float ev[9], ssum = 0.f;
#pragma unroll
    for (int o = 0; o < 9; ++o) { ev[o] = expf(__fadd_rn(lg[o], -mx)); ssum += ev[o]; }
    float leta[9];
    size_t ebase = ((size_t)(b * 30 + c) * 49 + cell) * 9;
#pragma unroll
    for (int o = 0; o < 9; ++o) {
      float e = __fdiv_rn(ev[o], ssum);
      o_eta[ebase + o] = e;
      leta[o] = logf(e);
    }
    uint32_t fb = (uint32_t)ebase;
    float best1 = -3.4e38f, best2 = -3.4e38f, pooledv = 0.f;
    int z2 = 0;
#pragma unroll
    for (int t = 0; t < 9; ++t) {
      float v1 = __fadd_rn(leta[t], gumbel_draw(KPOOL0, KPOOL1, fb + t));
      bool t1 = v1 > best1; best1 = t1 ? v1 : best1; pooledv = t1 ? tile[t] : pooledv;
      float v2 = __fadd_rn(leta[t], gumbel_draw(KUNP0, KUNP1, fb + t));
      bool t2 = v2 > best2; best2 = t2 ? v2 : best2; z2 = t2 ? t : z2;
    }
    pooled[g] = pooledv;
    ws_z[(size_t)b * 1470 + g] = (unsigned char)z2;
  }
  __syncthreads();

  // ---- phase 2: enc2 (4x4 conv over pooled) ----------------------------
  float* c2s = lds;          // 1280, overlays xs/w1s (safe after barrier)
  float* hs  = lds + 1280;   // 1280
  const int k2l = tid >> 4, pos = tid & 15;
  const int uy = pos >> 2, ux = pos & 3;
  {
    float acc[5] = {0.f, 0.f, 0.f, 0.f, 0.f};
    for (int c = 0; c < 30; ++c) {
      float pr[16];
#pragma unroll
      for (int dy = 0; dy < 4; ++dy)
#pragma unroll
        for (int dx = 0; dx < 4; ++dx)
          pr[dy * 4 + dx] = pooled[c * 49 + (uy + dy) * 7 + ux + dx];
#pragma unroll
      for (int j = 0; j < 5; ++j) {
        const float4* wr = (const float4*)&enc2_w[(size_t)((j * 16 + k2l) * 30 + c) * 16];
        float4 w0 = wr[0], w1 = wr[1], w2 = wr[2], w3 = wr[3];
        float a = acc[j];
        a = __fmaf_rn(pr[0],  w0.x, a);  a = __fmaf_rn(pr[1],  w0.y, a);
        a = __fmaf_rn(pr[2],  w0.z, a);  a = __fmaf_rn(pr[3],  w0.w, a);
        a = __fmaf_rn(pr[4],  w1.x, a);  a = __fmaf_rn(pr[5],  w1.y, a);
        a = __fmaf_rn(pr[6],  w1.z, a);  a = __fmaf_rn(pr[7],  w1.w, a);
        a = __fmaf_rn(pr[8],  w2.x, a);  a = __fmaf_rn(pr[9],  w2.y, a);
        a = __fmaf_rn(pr[10], w2.z, a);  a = __fmaf_rn(pr[11], w2.w, a);
        a = __fmaf_rn(pr[12], w3.x, a);  a = __fmaf_rn(pr[13], w3.y, a);
        a = __fmaf_rn(pr[14], w3.z, a);  a = __fmaf_rn(pr[15], w3.w, a);
        acc[j] = a;
      }
    }
#pragma unroll
    for (int j = 0; j < 5; ++j) c2s[(j * 16 + k2l) * 16 + pos] = acc[j];
  }
  __syncthreads();

  // ---- phase 3: per-channel code MLPs ----------------------------------
#pragma unroll
  for (int j = 0; j < 5; ++j) {
    int it = tid + j * 256;
    int k2 = it >> 4;
    const float4* wr4 = (const float4*)&h_w[(size_t)it * 16];
    float4 a0 = wr4[0], a1 = wr4[1], a2 = wr4[2], a3 = wr4[3];
    float wv16[16] = {a0.x, a0.y, a0.z, a0.w, a1.x, a1.y, a1.z, a1.w,
                      a2.x, a2.y, a2.z, a2.w, a3.x, a3.y, a3.z, a3.w};
    float d = 0.f;
#pragma unroll
    for (int i = 0; i < 16; ++i) d += c2s[k2 * 16 + i] * wv16[i];
    hs[it] = tanh_xla(__fadd_rn(d, h_b[it]));
  }
  __syncthreads();

#pragma unroll
  for (int j = 0; j < 5; ++j) {
    int it = tid + j * 256;
    int k2 = it >> 4;
    const float4* wm4 = (const float4*)&mean_w[(size_t)it * 16];
    const float4* wl4 = (const float4*)&lv_w[(size_t)it * 16];
    float4 m0 = wm4[0], m1 = wm4[1], m2 = wm4[2], m3 = wm4[3];
    float4 l0 = wl4[0], l1 = wl4[1], l2 = wl4[2], l3 = wl4[3];
    float wm16[16] = {m0.x, m0.y, m0.z, m0.w, m1.x, m1.y, m1.z, m1.w,
                      m2.x, m2.y, m2.z, m2.w, m3.x, m3.y, m3.z, m3.w};
    float wl16[16] = {l0.x, l0.y, l0.z, l0.w, l1.x, l1.y, l1.z, l1.w,
                      l2.x, l2.y, l2.z, l2.w, l3.x, l3.y, l3.z, l3.w};
    float dm = 0.f, dl = 0.f;
#pragma unroll
    for (int i = 0; i < 16; ++i) {
      float hv = hs[k2 * 16 + i];
      dm += hv * wm16[i];
      dl += hv * wl16[i];
    }
    float mean = __fadd_rn(dm, mean_b[it]);
    float lv = __fadd_rn(dl, lv_b[it]);
    size_t gi = (size_t)b * 1280 + it;
    o_mean[gi] = mean;
    o_lv[gi] = lv;
    float stdv = expf(__fmul_rn(0.5f, lv));
    float z = normal_draw(KCODE0, KCODE1, (uint32_t)(b * 1280 + it));
    ws_s[gi] = __fadd_rn(mean, __fmul_rn(stdv, z));
  }
}

// ---------------------------------------------------------------------------
// k_expand: Wexp[k=1280][t=1472] from dec2_w.
// ---------------------------------------------------------------------------
__global__ __launch_bounds__(256) void k_expand(const float* __restrict__ dec2_w,
                                                float* __restrict__ Wexp) {
  int idx = blockIdx.x * 256 + threadIdx.x;       // < 1280*1472
  int k = idx / 1472, t = idx - k * 1472;
  int k2 = k >> 4, iy = (k >> 2) & 3, ix = k & 3;
  int c = t / 49, cell = t - c * 49;
  int u = cell / 7, v = cell - u * 7;
  int du = u - iy, dv = v - ix;
  float val = 0.f;
  if (t < 1470 && (unsigned)du < 4u && (unsigned)dv < 4u)
    val = dec2_w[((k2 * 30 + c) << 4) + (du << 2) + dv];
  Wexp[idx] = val;
}

// ---------------------------------------------------------------------------
// k_gemm: S2[4096,1472] = A[4096,1280] x Wexp[1280,1472]
// ---------------------------------------------------------------------------
__global__ __launch_bounds__(256) void k_gemm(const float* __restrict__ A,
                                              const float* __restrict__ Bm,
                                              float* __restrict__ C) {
  __shared__ float As[16][132];
  __shared__ float Bs[16][64];
  const int tid = threadIdx.x;
  const int n0 = blockIdx.x * 64;
  const int m0 = blockIdx.y * 128;
  const int tx = tid & 15, ty = tid >> 4;

  float acc[8][4];
#pragma unroll
  for (int i = 0; i < 8; ++i)
#pragma unroll
    for (int j = 0; j < 4; ++j) acc[i][j] = 0.f;

  const int fa_r0 = tid >> 2, fa_c = (tid & 3) << 2;
  const int fb_k = tid >> 4, fb_c = (tid & 15) << 2;

  for (int k0 = 0; k0 < 1280; k0 += 16) {
    __syncthreads();
    float4 a0 = *(const float4*)&A[(size_t)(m0 + fa_r0) * 1280 + k0 + fa_c];
    float4 a1 = *(const float4*)&A[(size_t)(m0 + 64 + fa_r0) * 1280 + k0 + fa_c];
    float4 bv = *(const float4*)&Bm[(size_t)(k0 + fb_k) * 1472 + n0 + fb_c];
    As[fa_c + 0][fa_r0] = a0.x;  As[fa_c + 1][fa_r0] = a0.y;
    As[fa_c + 2][fa_r0] = a0.z;  As[fa_c + 3][fa_r0] = a0.w;
    As[fa_c + 0][64 + fa_r0] = a1.x;  As[fa_c + 1][64 + fa_r0] = a1.y;
    As[fa_c + 2][64 + fa_r0] = a1.z;  As[fa_c + 3][64 + fa_r0] = a1.w;
    *(float4*)&Bs[fb_k][fb_c] = bv;
    __syncthreads();

#pragma unroll
    for (int kk = 0; kk < 16; ++kk) {
      float4 av0 = *(const float4*)&As[kk][ty * 8];
      float4 av1 = *(const float4*)&As[kk][ty * 8 + 4];
      float4 bv0 = *(const float4*)&Bs[kk][tx * 4];
      float am[8] = {av0.x, av0.y, av0.z, av0.w, av1.x, av1.y, av1.z, av1.w};
      float bn[4] = {bv0.x, bv0.y, bv0.z, bv0.w};
#pragma unroll
      for (int i = 0; i < 8; ++i)
#pragma unroll
        for (int j = 0; j < 4; ++j) acc[i][j] = __fmaf_rn(am[i], bn[j], acc[i][j]);
    }
  }

#pragma unroll
  for (int i = 0; i < 8; ++i) {
    size_t row = (size_t)(m0 + ty * 8 + i);
    float4 o = make_float4(acc[i][0], acc[i][1], acc[i][2], acc[i][3]);
    *(float4*)&C[row * 1472 + n0 + tx * 4] = o;
  }
}

// ---------------------------------------------------------------------------
// k_unpool (gather, no atomics). Fixed 4x4 candidate window per pixel,
// fully unrolled, predicated; (val, py, px) packed in float2 -> ds_read_b64.
// Valid-term summation order identical (c asc, n asc, m asc).
// ---------------------------------------------------------------------------
__global__ __launch_bounds__(256) void k_unpool(
    const float* __restrict__ S2, const unsigned char* __restrict__ ws_z,
    const float* __restrict__ dec1_w, const float* __restrict__ alpha,
    float* __restrict__ o_xrec) {
  __shared__ float w1s[1920];
  __shared__ float2 tv[1470];   // {val, bitcast(py | px<<8)}
  const int b = blockIdx.x, tid = threadIdx.x;

  for (int i = tid; i < 1920; i += 256) w1s[i] = dec1_w[i];
#pragma unroll
  for (int j = 0; j < 6; ++j) {
    int t = tid + j * 256;
    if (t < 1470) {
      int c = t / 49, cell = t - c * 49;
      int n = cell / 7, m = cell - n * 7;
      int z = ws_z[(size_t)b * 1470 + t];
      int p = z / 3, q = z - p * 3;
      float val = S2[(size_t)b * 1472 + t];
      tv[t] = make_float2(val, __uint_as_float((uint32_t)((n * 3 + p) | ((m * 3 + q) << 8))));
    }
  }
  __syncthreads();

  float inva = __fdiv_rn(1.0f, alpha[0]);
  for (int pix = tid; pix < 784; pix += 256) {
    int y = pix / 28, x = pix - y * 28;
    int nlo = (y >= 9) ? ((y - 9 + 2) / 3) : 0;
    int nhi = min(6, y / 3);
    int mlo = (x >= 9) ? ((x - 9 + 2) / 3) : 0;
    int mhi = min(6, x / 3);

    float acc = 0.f;
    for (int c = 0; c < 30; ++c) {
      const float2* tvc = &tv[c * 49];
      const float* wc = &w1s[c * 64];
#pragma unroll
      for (int dn = 0; dn < 4; ++dn) {
        int n = nlo + dn;
        bool nok = n <= nhi;
        int nn = nok ? n : nhi;           // safe LDS index
#pragma unroll
        for (int dm = 0; dm < 4; ++dm) {
          int m = mlo + dm;
          bool ok = nok && (m <= mhi);
          int mm = (m <= mhi) ? m : mhi;  // safe LDS index
          float2 tvv = tvc[nn * 7 + mm];
          uint32_t pp = __float_as_uint(tvv.y);
          int dy = y - (int)(pp & 0xffu);
          int dx = x - (int)(pp >> 8);
          ok = ok && ((unsigned)dy < 8u) && ((unsigned)dx < 8u);
          float wvv = wc[((dy & 7) << 3) + (dx & 7)];
          acc = __fmaf_rn(ok ? tvv.x : 0.f, wvv, acc);
        }
      }
    }
    if (y == x) {
      float zn = normal_draw(KNOIS0, KNOIS1, (uint32_t)(b * 784 + pix));
      acc = __fadd_rn(acc, __fmul_rn(inva, zn));
    }
    o_xrec[(size_t)b * 784 + pix] = acc;
  }
}

// ---------------------------------------------------------------------------
extern "C" void kernel_launch(void* const* d_in, const int* in_sizes, int n_in,
                              void* d_out, int out_size, void* d_ws, size_t ws_size,
                              hipStream_t stream) {
  const float* x      = (const float*)d_in[0];
  const float* enc1_w = (const float*)d_in[1];
  const float* pw1    = (const float*)d_in[2];
  const float* pw2    = (const float*)d_in[3];
  const float* enc2_w = (const float*)d_in[4];
  const float* h_w    = (const float*)d_in[5];
  const float* h_b    = (const float*)d_in[6];
  const float* mean_w = (const float*)d_in[7];
  const float* mean_b = (const float*)d_in[8];
  const float* lv_w   = (const float*)d_in[9];
  const float* lv_b   = (const float*)d_in[10];
  const float* dec2_w = (const float*)d_in[11];
  const float* dec1_w = (const float*)d_in[12];
  const float* alpha  = (const float*)d_in[13];

  float* out = (float*)d_out;
  float* o_xrec = out;
  float* o_mean = out + OFF_MEAN;
  float* o_lv   = out + OFF_LV;
  float* o_eta  = out + OFF_ETA;

  char* wsb = (char*)d_ws;
  float* ws_s = (float*)wsb;
  unsigned char* ws_z = (unsigned char*)(wsb + 20971520);
  float* Wexp = (float*)(wsb + 26992640);
  float* S2   = (float*)(wsb + 34529280);

  k_expand<<<dim3(7360), dim3(256), 0, stream>>>(dec2_w, Wexp);
  k_enc<<<dim3(4096), dim3(256), 0, stream>>>(
      x, enc1_w, pw1, pw2, enc2_w, h_w, h_b, mean_w, mean_b, lv_w, lv_b,
      o_mean, o_lv, o_eta, ws_s, ws_z);
  k_gemm<<<dim3(23, 32), dim3(256), 0, stream>>>(ws_s, Wexp, S2);
  k_unpool<<<dim3(4096), dim3(256), 0, stream>>>(S2, ws_z, dec1_w, alpha, o_xrec);
}

// Round 5
// 1646.430 us; speedup vs baseline: 2.2969x; 1.0266x over previous
//
#include <hip/hip_runtime.h>
#include <cstdint>

// ---------------------------------------------------------------------------
// DGDN forward (B=4096). Outputs (f32, concat): x_rec[4096,1,28,28],
// mean[4096,80,16], log_var[4096,80,16], eta[4096,30,7,7,9].
// RNG: JAX threefry2x32, jax_threefry_partitionable=True reconstruction.
// R4 (resubmit after infra failure): k_gemm BM=64/BN=128/4x8 micro, 768
// blocks (3/CU exact), pipelined global loads. k_unpool 2 batches/block.
// ---------------------------------------------------------------------------

#define OFF_MEAN 3211264
#define OFF_LV   8454144
#define OFF_ETA  13697024

// ------------------------- threefry2x32 (constexpr) ------------------------
constexpr uint64_t ctf(uint32_t k0, uint32_t k1, uint32_t x0, uint32_t x1) {
  uint32_t ks0 = k0, ks1 = k1, ks2 = k0 ^ k1 ^ 0x1BD11BDAu;
  const int rotA[4] = {13, 15, 26, 6};
  const int rotB[4] = {17, 29, 16, 24};
  x0 += ks0; x1 += ks1;
  for (int g = 0; g < 5; ++g) {
    for (int i = 0; i < 4; ++i) {
      int r = (g & 1) ? rotB[i] : rotA[i];
      x0 += x1;
      x1 = (uint32_t)((x1 << r) | (x1 >> (32 - r)));
      x1 ^= x0;
    }
    uint32_t ka = (g + 1) % 3 == 0 ? ks0 : ((g + 1) % 3 == 1 ? ks1 : ks2);
    uint32_t kb = (g + 2) % 3 == 0 ? ks0 : ((g + 2) % 3 == 1 ? ks1 : ks2);
    x0 += ka;
    x1 += kb + (uint32_t)(g + 1);
  }
  return ((uint64_t)x0 << 32) | (uint64_t)x1;
}

constexpr uint64_t KP_ = ctf(0u, 42u, 0u, 0u);  // k_pool
constexpr uint64_t KU_ = ctf(0u, 42u, 0u, 1u);  // k_unpool
constexpr uint64_t KC_ = ctf(0u, 42u, 0u, 2u);  // k_code
constexpr uint64_t KN_ = ctf(0u, 42u, 0u, 3u);  // k_noise
constexpr uint32_t KPOOL0 = (uint32_t)(KP_ >> 32), KPOOL1 = (uint32_t)KP_;
constexpr uint32_t KUNP0  = (uint32_t)(KU_ >> 32), KUNP1  = (uint32_t)KU_;
constexpr uint32_t KCODE0 = (uint32_t)(KC_ >> 32), KCODE1 = (uint32_t)KC_;
constexpr uint32_t KNOIS0 = (uint32_t)(KN_ >> 32), KNOIS1 = (uint32_t)KN_;

// ------------------------- device threefry + draws -------------------------
__device__ __forceinline__ uint2 tf_dev(uint32_t k0, uint32_t k1, uint32_t x0, uint32_t x1) {
  uint32_t ks2 = k0 ^ k1 ^ 0x1BD11BDAu;
  x0 += k0; x1 += k1;
#define TFR(r) { x0 += x1; x1 = (x1 << (r)) | (x1 >> (32 - (r))); x1 ^= x0; }
  TFR(13) TFR(15) TFR(26) TFR(6)
  x0 += k1;  x1 += ks2 + 1u;
  TFR(17) TFR(29) TFR(16) TFR(24)
  x0 += ks2; x1 += k0 + 2u;
  TFR(13) TFR(15) TFR(26) TFR(6)
  x0 += k0;  x1 += k1 + 3u;
  TFR(17) TFR(29) TFR(16) TFR(24)
  x0 += k1;  x1 += ks2 + 4u;
  TFR(13) TFR(15) TFR(26) TFR(6)
  x0 += ks2; x1 += k0 + 5u;
#undef TFR
  return make_uint2(x0, x1);
}

__device__ __forceinline__ uint32_t rbits32(uint32_t k0, uint32_t k1, uint32_t idx) {
  uint2 r = tf_dev(k0, k1, 0u, idx);
  return r.x ^ r.y;
}

__device__ __forceinline__ float u01_from_bits(uint32_t bits) {
  return __uint_as_float((bits >> 9) | 0x3F800000u) - 1.0f;
}

__device__ __forceinline__ float gumbel_draw(uint32_t k0, uint32_t k1, uint32_t idx) {
  float u01 = u01_from_bits(rbits32(k0, k1, idx));
  float u = fmaxf(__fadd_rn(u01, 1.17549435e-38f), 1.17549435e-38f);
  return -logf(-logf(u));
}

__device__ __forceinline__ float erfinv_xla(float x) {
  float t = __fmul_rn(x, x);
  float w = -log1pf(-t);
  float p;
  if (w < 5.0f) {
    w = __fadd_rn(w, -2.5f);
    p = 2.81022636e-08f;
    p = __fadd_rn(__fmul_rn(p, w), 3.43273939e-07f);
    p = __fadd_rn(__fmul_rn(p, w), -3.5233877e-06f);
    p = __fadd_rn(__fmul_rn(p, w), -4.39150654e-06f);
    p = __fadd_rn(__fmul_rn(p, w), 0.00021858087f);
    p = __fadd_rn(__fmul_rn(p, w), -0.00125372503f);
    p = __fadd_rn(__fmul_rn(p, w), -0.00417768164f);
    p = __fadd_rn(__fmul_rn(p, w), 0.246640727f);
    p = __fadd_rn(__fmul_rn(p, w), 1.50140941f);
  } else {
    w = __fadd_rn(sqrtf(w), -3.0f);
    p = -0.000200214257f;
    p = __fadd_rn(__fmul_rn(p, w), 0.000100950558f);
    p = __fadd_rn(__fmul_rn(p, w), 0.00134934322f);
    p = __fadd_rn(__fmul_rn(p, w), -0.00367342844f);
    p = __fadd_rn(__fmul_rn(p, w), 0.00573950773f);
    p = __fadd_rn(__fmul_rn(p, w), -0.0076224613f);
    p = __fadd_rn(__fmul_rn(p, w), 0.00943887047f);
    p = __fadd_rn(__fmul_rn(p, w), 1.00167406f);
    p = __fadd_rn(__fmul_rn(p, w), 2.83297682f);
  }
  return __fmul_rn(p, x);
}

__device__ __forceinline__ float normal_draw(uint32_t k0, uint32_t k1, uint32_t idx) {
  float u01 = u01_from_bits(rbits32(k0, k1, idx));
  float u = fmaxf(__fadd_rn(__fmul_rn(u01, 2.0f), -0.99999994f), -0.99999994f);
  return __fmul_rn(1.41421356237309515f, erfinv_xla(u));
}

__device__ __forceinline__ float tanh_xla(float x) {
  float ax = fabsf(x);
  float xc = fmaxf(fminf(x, 7.90531110763549805f), -7.90531110763549805f);
  float x2 = __fmul_rn(xc, xc);
  float p = __fmaf_rn(x2, -2.76076847742355e-16f, 2.00018790482477e-13f);
  p = __fmaf_rn(x2, p, -8.60467152213735e-11f);
  p = __fmaf_rn(x2, p, 5.12229709037114e-08f);
  p = __fmaf_rn(x2, p, 1.48572235717979e-05f);
  p = __fmaf_rn(x2, p, 6.37261928875436e-04f);
  p = __fmaf_rn(x2, p, 4.89352455891786e-03f);
  p = __fmul_rn(xc, p);
  float q = __fmaf_rn(x2, 1.19825839466702e-06f, 1.18534705686654e-04f);
  q = __fmaf_rn(x2, q, 2.26843463243900e-03f);
  q = __fmaf_rn(x2, q, 4.89352518554385e-03f);
  return (ax < 0.0004f) ? x : __fdiv_rn(p, q);
}

// ---------------------------------------------------------------------------
// Encoder (unchanged from verified round-3 kernel).
// ---------------------------------------------------------------------------
__global__ __launch_bounds__(256) void k_enc(
    const float* __restrict__ x, const float* __restrict__ enc1_w,
    const float* __restrict__ pw1, const float* __restrict__ pw2,
    const float* __restrict__ enc2_w, const float* __restrict__ h_w,
    const float* __restrict__ h_b, const float* __restrict__ mean_w,
    const float* __restrict__ mean_b, const float* __restrict__ lv_w,
    const float* __restrict__ lv_b,
    float* __restrict__ o_mean, float* __restrict__ o_lv, float* __restrict__ o_eta,
    float* __restrict__ ws_s, unsigned char* __restrict__ ws_z) {
  __shared__ float lds[2866];
  __shared__ float pooled[1470];
  const int b = blockIdx.x, tid = threadIdx.x;

  float* xs  = lds;
  float* w1s = lds + 784;
  float* pp1 = lds + 2704;
  float* pp2 = lds + 2785;
  for (int i = tid; i < 784; i += 256) xs[i] = x[(size_t)b * 784 + i];
  for (int i = tid; i < 1920; i += 256) w1s[i] = enc1_w[i];
  if (tid < 81) { pp1[tid] = pw1[tid]; pp2[tid] = pw2[tid]; }
  __syncthreads();

  for (int g = tid; g < 1470; g += 256) {
    const int c = g / 49, cell = g - c * 49;
    const int n = cell / 7, m = cell - n * 7;
    const int yb = n * 3, xb = m * 3;
    const float* wc = &w1s[c * 64];

    float R[3][10];
#pragma unroll
    for (int rr = 0; rr < 3; ++rr)
#pragma unroll
      for (int i = 0; i < 10; ++i) R[rr][i] = xs[(yb + rr) * 28 + xb + i];

    float tile[9];
#pragma unroll
    for (int i = 0; i < 9; ++i) tile[i] = 0.f;

#pragma unroll
    for (int dy = 0; dy < 8; ++dy) {
      float4 wa = *(const float4*)&wc[dy * 8];
      float4 wb = *(const float4*)&wc[dy * 8 + 4];
      float w8[8] = {wa.x, wa.y, wa.z, wa.w, wb.x, wb.y, wb.z, wb.w};
#pragma unroll
      for (int dx = 0; dx < 8; ++dx) {
        float w = w8[dx];
#pragma unroll
        for (int p = 0; p < 3; ++p)
#pragma unroll
          for (int q = 0; q < 3; ++q)
            tile[p * 3 + q] = __fmaf_rn(R[(dy + p) % 3][dx + q], w, tile[p * 3 + q]);
      }
      if (dy < 7) {
#pragma unroll
        for (int i = 0; i < 10; ++i) R[dy % 3][i] = xs[(yb + dy + 3) * 28 + xb + i];
      }
    }

    float h1v[9];
#pragma unroll
    for (int o = 0; o < 9; ++o) {
      float a = 0.f;
#pragma unroll
      for (int t = 0; t < 9; ++t) a += tile[t] * pp1[o * 9 + t];
      h1v[o] = tanh_xla(a);
    }
    float lg[9], mx = -3.4e38f;
#pragma unroll
    for (int o = 0; o < 9; ++o) {
      float a = 0.f;
#pragma unroll
      for (int t = 0; t < 9; ++t) a += h1v[t] * pp2[o * 9 + t];
      lg[o] = a;
      mx = fmaxf(mx, a);
    }
    float ev[9], ssum = 0.f;
#pragma unroll
    for (int o = 0; o < 9; ++o) { ev[o] = expf(__fadd_rn(lg[o], -mx)); ssum += ev[o]; }
    float leta[9];
    size_t ebase = ((size_t)(b * 30 + c) * 49 + cell) * 9;
#pragma unroll
    for (int o = 0; o < 9; ++o) {
      float e = __fdiv_rn(ev[o], ssum);
      o_eta[ebase + o] = e;
      leta[o] = logf(e);
    }
    uint32_t fb = (uint32_t)ebase;
    float best1 = -3.4e38f, best2 = -3.4e38f, pooledv = 0.f;
    int z2 = 0;
#pragma unroll
    for (int t = 0; t < 9; ++t) {
      float v1 = __fadd_rn(leta[t], gumbel_draw(KPOOL0, KPOOL1, fb + t));
      bool t1 = v1 > best1; best1 = t1 ? v1 : best1; pooledv = t1 ? tile[t] : pooledv;
      float v2 = __fadd_rn(leta[t], gumbel_draw(KUNP0, KUNP1, fb + t));
      bool t2 = v2 > best2; best2 = t2 ? v2 : best2; z2 = t2 ? t : z2;
    }
    pooled[g] = pooledv;
    ws_z[(size_t)b * 1470 + g] = (unsigned char)z2;
  }
  __syncthreads();

  float* c2s = lds;
  float* hs  = lds + 1280;
  const int k2l = tid >> 4, pos = tid & 15;
  const int uy = pos >> 2, ux = pos & 3;
  {
    float acc[5] = {0.f, 0.f, 0.f, 0.f, 0.f};
    for (int c = 0; c < 30; ++c) {
      float pr[16];
#pragma unroll
      for (int dy = 0; dy < 4; ++dy)
#pragma unroll
        for (int dx = 0; dx < 4; ++dx)
          pr[dy * 4 + dx] = pooled[c * 49 + (uy + dy) * 7 + ux + dx];
#pragma unroll
      for (int j = 0; j < 5; ++j) {
        const float4* wr = (const float4*)&enc2_w[(size_t)((j * 16 + k2l) * 30 + c) * 16];
        float4 w0 = wr[0], w1 = wr[1], w2 = wr[2], w3 = wr[3];
        float a = acc[j];
        a = __fmaf_rn(pr[0],  w0.x, a);  a = __fmaf_rn(pr[1],  w0.y, a);
        a = __fmaf_rn(pr[2],  w0.z, a);  a = __fmaf_rn(pr[3],  w0.w, a);
        a = __fmaf_rn(pr[4],  w1.x, a);  a = __fmaf_rn(pr[5],  w1.y, a);
        a = __fmaf_rn(pr[6],  w1.z, a);  a = __fmaf_rn(pr[7],  w1.w, a);
        a = __fmaf_rn(pr[8],  w2.x, a);  a = __fmaf_rn(pr[9],  w2.y, a);
        a = __fmaf_rn(pr[10], w2.z, a);  a = __fmaf_rn(pr[11], w2.w, a);
        a = __fmaf_rn(pr[12], w3.x, a);  a = __fmaf_rn(pr[13], w3.y, a);
        a = __fmaf_rn(pr[14], w3.z, a);  a = __fmaf_rn(pr[15], w3.w, a);
        acc[j] = a;
      }
    }
#pragma unroll
    for (int j = 0; j < 5; ++j) c2s[(j * 16 + k2l) * 16 + pos] = acc[j];
  }
  __syncthreads();

#pragma unroll
  for (int j = 0; j < 5; ++j) {
    int it = tid + j * 256;
    int k2 = it >> 4;
    const float4* wr4 = (const float4*)&h_w[(size_t)it * 16];
    float4 a0 = wr4[0], a1 = wr4[1], a2 = wr4[2], a3 = wr4[3];
    float wv16[16] = {a0.x, a0.y, a0.z, a0.w, a1.x, a1.y, a1.z, a1.w,
                      a2.x, a2.y, a2.z, a2.w, a3.x, a3.y, a3.z, a3.w};
    float d = 0.f;
#pragma unroll
    for (int i = 0; i < 16; ++i) d += c2s[k2 * 16 + i] * wv16[i];
    hs[it] = tanh_xla(__fadd_rn(d, h_b[it]));
  }
  __syncthreads();

#pragma unroll
  for (int j = 0; j < 5; ++j) {
    int it = tid + j * 256;
    int k2 = it >> 4;
    const float4* wm4 = (const float4*)&mean_w[(size_t)it * 16];
    const float4* wl4 = (const float4*)&lv_w[(size_t)it * 16];
    float4 m0 = wm4[0], m1 = wm4[1], m2 = wm4[2], m3 = wm4[3];
    float4 l0 = wl4[0], l1 = wl4[1], l2 = wl4[2], l3 = wl4[3];
    float wm16[16] = {m0.x, m0.y, m0.z, m0.w, m1.x, m1.y, m1.z, m1.w,
                      m2.x, m2.y, m2.z, m2.w, m3.x, m3.y, m3.z, m3.w};
    float wl16[16] = {l0.x, l0.y, l0.z, l0.w, l1.x, l1.y, l1.z, l1.w,
                      l2.x, l2.y, l2.z, l2.w, l3.x, l3.y, l3.z, l3.w};
    float dm = 0.f, dl = 0.f;
#pragma unroll
    for (int i = 0; i < 16; ++i) {
      float hv = hs[k2 * 16 + i];
      dm += hv * wm16[i];
      dl += hv * wl16[i];
    }
    float mean = __fadd_rn(dm, mean_b[it]);
    float lv = __fadd_rn(dl, lv_b[it]);
    size_t gi = (size_t)b * 1280 + it;
    o_mean[gi] = mean;
    o_lv[gi] = lv;
    float stdv = expf(__fmul_rn(0.5f, lv));
    float z = normal_draw(KCODE0, KCODE1, (uint32_t)(b * 1280 + it));
    ws_s[gi] = __fadd_rn(mean, __fmul_rn(stdv, z));
  }
}

// ---------------------------------------------------------------------------
// k_expand: Wexp[k=1280][t=1472] from dec2_w.
// ---------------------------------------------------------------------------
__global__ __launch_bounds__(256) void k_expand(const float* __restrict__ dec2_w,
                                                float* __restrict__ Wexp) {
  int idx = blockIdx.x * 256 + threadIdx.x;       // < 1280*1472
  int k = idx / 1472, t = idx - k * 1472;
  int k2 = k >> 4, iy = (k >> 2) & 3, ix = k & 3;
  int c = t / 49, cell = t - c * 49;
  int u = cell / 7, v = cell - u * 7;
  int du = u - iy, dv = v - ix;
  float val = 0.f;
  if (t < 1470 && (unsigned)du < 4u && (unsigned)dv < 4u)
    val = dec2_w[((k2 * 30 + c) << 4) + (du << 2) + dv];
  Wexp[idx] = val;
}

// ---------------------------------------------------------------------------
// k_gemm: S2[4096,1472] = A[4096,1280] x Wexp[1280,1472]
// BM=64, BN=128, BK=16, 256 threads, 4x8 micro-tile. Grid (12,64)=768 blocks
// = exactly 3/CU. Global loads for tile k0+16 issue before compute of k0
// (software pipeline). Last N-tile: clamped loads, full-or-none masked
// stores. k ascending (k0 asc, kk asc, single accumulator) — summation
// order identical to previous verified kernel.
// ---------------------------------------------------------------------------
__global__ __launch_bounds__(256) void k_gemm(const float* __restrict__ A,
                                              const float* __restrict__ Bm,
                                              float* __restrict__ C) {
  __shared__ float As[16][68];    // [kk][m], pad to 68 for bank spread
  __shared__ float Bs[16][128];
  const int tid = threadIdx.x;
  const int n0 = blockIdx.x * 128;    // 12 tiles (last covers 64 valid cols)
  const int m0 = blockIdx.y * 64;     // 64 tiles
  const int tx = tid & 15, ty = tid >> 4;

  float acc[4][8];
#pragma unroll
  for (int i = 0; i < 4; ++i)
#pragma unroll
    for (int j = 0; j < 8; ++j) acc[i][j] = 0.f;

  // staging decomposition
  const int a_r = tid >> 2, a_c = (tid & 3) << 2;    // A: 1 float4/thread
  const int b_k = tid >> 4, b_c = (tid & 15) << 3;   // B: 2 float4/thread
  const int bcol = n0 + b_c;
  const int bcol_c = (bcol > 1464) ? 1464 : bcol;    // clamp (garbage unused)

  const float* pa = &A[(size_t)(m0 + a_r) * 1280 + a_c];
  const float* pb = &Bm[(size_t)b_k * 1472 + bcol_c];

  // prologue: load tile k0=0
  float4 av = *(const float4*)pa;
  float4 bv0 = *(const float4*)pb;
  float4 bv1 = *(const float4*)(pb + 4);

  for (int k0 = 0; k0 < 1280; k0 += 16) {
    __syncthreads();
    As[a_c + 0][a_r] = av.x;  As[a_c + 1][a_r] = av.y;
    As[a_c + 2][a_r] = av.z;  As[a_c + 3][a_r] = av.w;
    *(float4*)&Bs[b_k][b_c] = bv0;
    *(float4*)&Bs[b_k][b_c + 4] = bv1;
    __syncthreads();

    if (k0 + 16 < 1280) {   // prefetch next tile (latency hides under FMAs)
      av = *(const float4*)(pa + k0 + 16);
      bv0 = *(const float4*)(pb + (size_t)(k0 + 16) * 1472);
      bv1 = *(const float4*)(pb + (size_t)(k0 + 16) * 1472 + 4);
    }

#pragma unroll
    for (int kk = 0; kk < 16; ++kk) {
      float4 a4 = *(const float4*)&As[kk][ty * 4];
      float4 b4a = *(const float4*)&Bs[kk][tx * 8];
      float4 b4b = *(const float4*)&Bs[kk][tx * 8 + 4];
      float am[4] = {a4.x, a4.y, a4.z, a4.w};
      float bn[8] = {b4a.x, b4a.y, b4a.z, b4a.w, b4b.x, b4b.y, b4b.z, b4b.w};
#pragma unroll
      for (int i = 0; i < 4; ++i)
#pragma unroll
        for (int j = 0; j < 8; ++j) acc[i][j] = __fmaf_rn(am[i], bn[j], acc[i][j]);
    }
  }

  if (n0 + tx * 8 < 1472) {   // full-or-none (valid width is multiple of 8)
#pragma unroll
    for (int i = 0; i < 4; ++i) {
      size_t row = (size_t)(m0 + ty * 4 + i);
      float4 o0 = make_float4(acc[i][0], acc[i][1], acc[i][2], acc[i][3]);
      float4 o1 = make_float4(acc[i][4], acc[i][5], acc[i][6], acc[i][7]);
      *(float4*)&C[row * 1472 + n0 + tx * 8] = o0;
      *(float4*)&C[row * 1472 + n0 + tx * 8 + 4] = o1;
    }
  }
}

// ---------------------------------------------------------------------------
// k_unpool (gather, no atomics). 2 batches per block: w1s staged once,
// pixel-loop lane utilization 1568/(7*256)=87.5% (was 76.6%). Inner gather
// identical to verified round-3 form (c asc, n asc, m asc).
// ---------------------------------------------------------------------------
__global__ __launch_bounds__(256) void k_unpool(
    const float* __restrict__ S2, const unsigned char* __restrict__ ws_z,
    const float* __restrict__ dec1_w, const float* __restrict__ alpha,
    float* __restrict__ o_xrec) {
  __shared__ float w1s[1920];
  __shared__ float2 tv[2][1470];   // {val, bitcast(py | px<<8)} per batch
  const int b0 = blockIdx.x * 2, tid = threadIdx.x;

  for (int i = tid; i < 1920; i += 256) w1s[i] = dec1_w[i];
  for (int t = tid; t < 2940; t += 256) {
    int bb = t >= 1470;
    int tt = t - bb * 1470;
    int c = tt / 49, cell = tt - c * 49;
    int n = cell / 7, m = cell - n * 7;
    int b = b0 + bb;
    int z = ws_z[(size_t)b * 1470 + tt];
    int p = z / 3, q = z - p * 3;
    float val = S2[(size_t)b * 1472 + tt];
    tv[bb][tt] = make_float2(val, __uint_as_float((uint32_t)((n * 3 + p) | ((m * 3 + q) << 8))));
  }
  __syncthreads();

  float inva = __fdiv_rn(1.0f, alpha[0]);
  for (int pix = tid; pix < 1568; pix += 256) {
    int bb = pix >= 784;
    int p2 = pix - bb * 784;
    int b = b0 + bb;
    int y = p2 / 28, x = p2 - y * 28;
    int nlo = (y >= 9) ? ((y - 9 + 2) / 3) : 0;
    int nhi = min(6, y / 3);
    int mlo = (x >= 9) ? ((x - 9 + 2) / 3) : 0;
    int mhi = min(6, x / 3);

    float acc = 0.f;
    const float2* tvb = tv[bb];
    for (int c = 0; c < 30; ++c) {
      const float2* tvc = &tvb[c * 49];
      const float* wc = &w1s[c * 64];
#pragma unroll
      for (int dn = 0; dn < 4; ++dn) {
        int n = nlo + dn;
        bool nok = n <= nhi;
        int nn = nok ? n : nhi;
#pragma unroll
        for (int dm = 0; dm < 4; ++dm) {
          int m = mlo + dm;
          bool ok = nok && (m <= mhi);
          int mm = (m <= mhi) ? m : mhi;
          float2 tvv = tvc[nn * 7 + mm];
          uint32_t pp = __float_as_uint(tvv.y);
          int dy = y - (int)(pp & 0xffu);
          int dx = x - (int)(pp >> 8);
          ok = ok && ((unsigned)dy < 8u) && ((unsigned)dx < 8u);
          float wvv = wc[((dy & 7) << 3) + (dx & 7)];
          acc = __fmaf_rn(ok ? tvv.x : 0.f, wvv, acc);
        }
      }
    }
    if (y == x) {
      float zn = normal_draw(KNOIS0, KNOIS1, (uint32_t)(b * 784 + p2));
      acc = __fadd_rn(acc, __fmul_rn(inva, zn));
    }
    o_xrec[(size_t)b * 784 + p2] = acc;
  }
}

// ---------------------------------------------------------------------------
extern "C" void kernel_launch(void* const* d_in, const int* in_sizes, int n_in,
                              void* d_out, int out_size, void* d_ws, size_t ws_size,
                              hipStream_t stream) {
  const float* x      = (const float*)d_in[0];
  const float* enc1_w = (const float*)d_in[1];
  const float* pw1    = (const float*)d_in[2];
  const float* pw2    = (const float*)d_in[3];
  const float* enc2_w = (const float*)d_in[4];
  const float* h_w    = (const float*)d_in[5];
  const float* h_b    = (const float*)d_in[6];
  const float* mean_w = (const float*)d_in[7];
  const float* mean_b = (const float*)d_in[8];
  const float* lv_w   = (const float*)d_in[9];
  const float* lv_b   = (const float*)d_in[10];
  const float* dec2_w = (const float*)d_in[11];
  const float* dec1_w = (const float*)d_in[12];
  const float* alpha  = (const float*)d_in[13];

  float* out = (float*)d_out;
  float* o_xrec = out;
  float* o_mean = out + OFF_MEAN;
  float* o_lv   = out + OFF_LV;
  float* o_eta  = out + OFF_ETA;

  char* wsb = (char*)d_ws;
  float* ws_s = (float*)wsb;
  unsigned char* ws_z = (unsigned char*)(wsb + 20971520);
  float* Wexp = (float*)(wsb + 26992640);
  float* S2   = (float*)(wsb + 34529280);

  k_expand<<<dim3(7360), dim3(256), 0, stream>>>(dec2_w, Wexp);
  k_enc<<<dim3(4096), dim3(256), 0, stream>>>(
      x, enc1_w, pw1, pw2, enc2_w, h_w, h_b, mean_w, mean_b, lv_w, lv_b,
      o_mean, o_lv, o_eta, ws_s, ws_z);
  k_gemm<<<dim3(12, 64), dim3(256), 0, stream>>>(ws_s, Wexp, S2);
  k_unpool<<<dim3(2048), dim3(256), 0, stream>>>(S2, ws_z, dec1_w, alpha, o_xrec);
}